// Round 4
// baseline (282.775 us; speedup 1.0000x reference)
//
#include <hip/hip_runtime.h>
#include <math.h>

#define BB 8
#define NN 2048
#define CC 128
#define KNB 16
#define BN (BB*NN)
#define WPAD 132       // LDS row pad, 16B-aligned rows (264B row stride)

#define EMPTYK 0xFFFFFFFFFFFFFFFFULL

typedef __attribute__((ext_vector_type(8))) short short8;
typedef __attribute__((ext_vector_type(4))) float floatx4;
typedef __attribute__((ext_vector_type(4), aligned(4))) float floatx4u;  // 4B-aligned float4

// fast silu: x / (1 + e^-x) via v_exp_f32 + v_rcp_f32 (~1 ulp, plenty here)
__device__ __forceinline__ float silu_f(float x) {
  const float e = __builtin_amdgcn_exp2f(-1.442695040888963f * x);
  return x * __builtin_amdgcn_rcpf(1.0f + e);
}
__device__ __forceinline__ float fsqrt(float x) { return __builtin_amdgcn_sqrtf(x); }
__device__ __forceinline__ float frcp(float x)  { return __builtin_amdgcn_rcpf(x); }

__device__ __forceinline__ unsigned long long umin64(unsigned long long a, unsigned long long b) {
  return (b < a) ? b : a;
}

__device__ __forceinline__ unsigned short f2bf(float f) {   // RNE
  unsigned u = __float_as_uint(f);
  unsigned r = u + 0x7FFFu + ((u >> 16) & 1u);
  return (unsigned short)(r >> 16);
}
__device__ __forceinline__ float bf2f(unsigned short s) {
  return __uint_as_float(((unsigned)s) << 16);
}

// 8-wide dot: 2 float4 loads (L1-resident weights) + 8 FMA
__device__ __forceinline__ float dot8(const float* __restrict__ w, const float* __restrict__ h) {
  const float4 a = *(const float4*)w;
  const float4 b = *(const float4*)(w + 4);
  float s = a.x*h[0];
  s = fmaf(a.y, h[1], s); s = fmaf(a.z, h[2], s); s = fmaf(a.w, h[3], s);
  s = fmaf(b.x, h[4], s); s = fmaf(b.y, h[5], s); s = fmaf(b.z, h[6], s);
  s = fmaf(b.w, h[7], s);
  return s;
}

// ---------------------------------------------------------------------------
// Kernel 0: per-point squared-norm in f64 (bitwise-identical expression to
// the old in-loop computation). Removes 5 f64 ops/pair from the knn loop.
// ---------------------------------------------------------------------------
__global__ __launch_bounds__(256) void sq_kernel(const float* __restrict__ x,
                                                 double* __restrict__ sqd) {
  const int i = blockIdx.x*256 + threadIdx.x;      // 0..BN-1
  const double a0 = (double)x[i*3+0], a1 = (double)x[i*3+1], a2 = (double)x[i*3+2];
  sqd[i] = a0*a0 + a1*a1 + a2*a2;
}

// ---------------------------------------------------------------------------
// Kernel 1: kNN — one WAVE per query, 4 waves/block, no LDS, no barriers.
// sqm now loaded from the precomputed f64 table (identical values).
// Selection: u32 high-word butterfly + ballot/readlane, exact low-word
// fallback on ties (bitwise-identical ordering to the u64 butterfly).
// ---------------------------------------------------------------------------
__global__ __launch_bounds__(256) void knn_kernel(const float* __restrict__ x,
                                                  const double* __restrict__ sqd,
                                                  int* __restrict__ idx) {
  const int lane = threadIdx.x & 63;
  const int wave = threadIdx.x >> 6;
  const int bn = blockIdx.x * 4 + wave;
  const int b = bn >> 11;
  const int n = bn & (NN - 1);

  const float* xb = x + (size_t)b * NN * 3;
  const double* sqb = sqd + (size_t)b * NN;
  const double xn0 = (double)xb[n*3+0], xn1 = (double)xb[n*3+1], xn2 = (double)xb[n*3+2];
  const double sqn = sqb[n];

  unsigned long long k[32];
  unsigned long long t0 = EMPTYK, t1 = EMPTYK, t2 = EMPTYK, t3 = EMPTYK;

  #pragma unroll
  for (int i = 0; i < 32; ++i) {
    const int m = i*64 + lane;
    const double a0 = (double)xb[m*3+0], a1 = (double)xb[m*3+1], a2 = (double)xb[m*3+2];
    const double sqm = sqb[m];
    const double dot = xn0*a0 + xn1*a1 + xn2*a2;
    const double d = sqn + sqm - 2.0*dot;
    unsigned long long kk =
        ((unsigned long long)__double_as_longlong(d) & ~2047ULL) | (unsigned long long)m;
    if (m == n) kk = 0x8000000000000000ULL | (unsigned long long)m;
    k[i] = kk;
    const bool l3 = kk < t3, l2 = kk < t2, l1 = kk < t1, l0 = kk < t0;
    t3 = l3 ? (l2 ? t2 : kk) : t3;
    t2 = l2 ? (l1 ? t1 : kk) : t2;
    t1 = l1 ? (l0 ? t0 : kk) : t1;
    t0 = l0 ? kk : t0;
  }

  int* op = idx + (size_t)bn * KNB;
  for (int t = 0; t < KNB; ++t) {
    const unsigned h0 = (unsigned)(t0 >> 32);
    const unsigned l0w = (unsigned)t0;
    unsigned hm = h0;
    #pragma unroll
    for (int off = 32; off > 0; off >>= 1) {
      const unsigned o = (unsigned)__shfl_xor((int)hm, off, 64);
      hm = (o < hm) ? o : hm;
    }
    const bool tied = (h0 == hm);
    const unsigned long long bal = __ballot(tied);
    unsigned lm;
    if (__builtin_popcountll(bal) == 1) {
      const int owner = __builtin_ctzll(bal);
      lm = (unsigned)__shfl((int)l0w, owner, 64);
    } else {
      lm = tied ? l0w : 0xFFFFFFFFu;
      #pragma unroll
      for (int off = 32; off > 0; off >>= 1) {
        const unsigned o = (unsigned)__shfl_xor((int)lm, off, 64);
        lm = (o < lm) ? o : lm;
      }
    }
    const unsigned long long g = ((unsigned long long)hm << 32) | (unsigned long long)lm;

    if (lane == 0) op[t] = (int)(lm & 2047u);

    const bool own = tied && (l0w == lm);
    t0 = own ? t1 : t0;
    t1 = own ? t2 : t1;
    t2 = own ? t3 : t2;
    t3 = own ? EMPTYK : t3;

    const bool need = (t0 == EMPTYK);
    if (__any(need)) {
      unsigned long long nm = EMPTYK;
      #pragma unroll
      for (int i = 0; i < 32; ++i) {
        const unsigned long long c = (k[i] > g) ? k[i] : EMPTYK;
        nm = umin64(nm, c);
      }
      t0 = need ? nm : t0;
    }
  }
}

// ---------------------------------------------------------------------------
// Kernel 1b: W pre-conversion — f32 -> bf16 hi/lo planes, once per matrix.
// ---------------------------------------------------------------------------
__global__ __launch_bounds__(256) void wconv_kernel(
    const float* __restrict__ Wq, const float* __restrict__ Wk, const float* __restrict__ Wu,
    unsigned short* __restrict__ Whl)
{
  const int i = blockIdx.x*256 + threadIdx.x;      // 0..49151
  const int mat = i >> 14, rem = i & 16383;
  const float* W = (mat == 0) ? Wq : ((mat == 1) ? Wk : Wu);
  const float f = W[rem];
  const unsigned short h = f2bf(f);
  const float r = f - bf2f(h);
  unsigned short* base = Whl + (size_t)mat * 2 * CC * CC;
  base[rem]           = h;
  base[CC*CC + rem]   = f2bf(r);
}

// ---------------------------------------------------------------------------
// Kernel 2: Q/K/U via bf16 split-precision MFMA, all three matrices per
// block. NEW: (a) outputs in INTERNAL layout [p][d][c] so epilogue stores
// are coalesced (16 consecutive floats per 16-lane group, 4 lines/store vs
// 12); (b) single-plane LDS (33.8 KB) with hi-pass then lo-pass -> 3
// blocks/CU instead of 2. Same MFMA/ds_read/stage counts as before.
// ---------------------------------------------------------------------------
__global__ __launch_bounds__(256, 2) void vn_gemm_mfma(
    const float* __restrict__ v, const unsigned short* __restrict__ Whl,
    float* __restrict__ Q, float* __restrict__ Kt, float* __restrict__ U)
{
  __shared__ short Wlds[CC][WPAD];

  const int tid  = threadIdx.x;
  const int lane = tid & 63;
  const int wave = tid >> 6;
  const int quad = lane >> 4;
  const int l15  = lane & 15;

  // ---- A tile: 16 m-rows per wave, full K=128; load + convert ONCE
  const int m = blockIdx.x*64 + wave*16 + l15;
  const int p = m / 3, d = m - 3*p;
  const float* vb = v + (size_t)p * (CC*3) + d;
  float areg[32];
  #pragma unroll
  for (int kc = 0; kc < 4; ++kc)
    #pragma unroll
    for (int j = 0; j < 8; ++j)
      areg[kc*8+j] = vb[(kc*32 + quad*8 + j)*3];

  short8 ah[4], al[4];
  #pragma unroll
  for (int kc = 0; kc < 4; ++kc)
    #pragma unroll
    for (int j = 0; j < 8; ++j) {
      const float f = areg[kc*8+j];
      unsigned short h = f2bf(f);
      float r = f - bf2f(h);
      ah[kc][j] = (short)h;
      al[kc][j] = (short)f2bf(r);
    }

  // store bases: row r=(pp,dd) -> pp*384 + dd*128, channel o added later
  const int r0s = blockIdx.x*64 + wave*16 + quad*4;
  int pbase[4];
  #pragma unroll
  for (int reg = 0; reg < 4; ++reg) {
    const int r = r0s + reg;
    const int pp = r / 3;
    pbase[reg] = pp * (CC*3) + (r - 3*pp) * CC;
  }

  for (int mat = 0; mat < 3; ++mat) {
    float* __restrict__ Out = (mat == 0) ? Q : ((mat == 1) ? Kt : U);
    const unsigned short* Wg = Whl + (size_t)mat * 2 * CC * CC;

    floatx4 acc[8];
    #pragma unroll
    for (int ct = 0; ct < 8; ++ct) acc[ct] = (floatx4){0.f, 0.f, 0.f, 0.f};

    // ---- pass 1: hi plane (ah*bh + al*bh)
    #pragma unroll
    for (int it = 0; it < 8; ++it) {
      const int i = it*256 + tid;          // 2048 short8 chunks
      const int o = i >> 4, c8 = (i & 15) * 8;
      *(short8*)&Wlds[o][c8] = *(const short8*)&Wg[o*CC + c8];
    }
    __syncthreads();
    #pragma unroll
    for (int kc = 0; kc < 4; ++kc) {
      #pragma unroll
      for (int ct = 0; ct < 8; ++ct) {
        const short8 bh = *(const short8*)&Wlds[ct*16 + l15][kc*32 + quad*8];
        acc[ct] = __builtin_amdgcn_mfma_f32_16x16x32_bf16(ah[kc], bh, acc[ct], 0, 0, 0);
        acc[ct] = __builtin_amdgcn_mfma_f32_16x16x32_bf16(al[kc], bh, acc[ct], 0, 0, 0);
      }
    }
    __syncthreads();

    // ---- pass 2: lo plane (ah*bl)
    #pragma unroll
    for (int it = 0; it < 8; ++it) {
      const int i = it*256 + tid;
      const int o = i >> 4, c8 = (i & 15) * 8;
      *(short8*)&Wlds[o][c8] = *(const short8*)&Wg[CC*CC + o*CC + c8];
    }
    __syncthreads();
    #pragma unroll
    for (int kc = 0; kc < 4; ++kc) {
      #pragma unroll
      for (int ct = 0; ct < 8; ++ct) {
        const short8 bl = *(const short8*)&Wlds[ct*16 + l15][kc*32 + quad*8];
        acc[ct] = __builtin_amdgcn_mfma_f32_16x16x32_bf16(ah[kc], bl, acc[ct], 0, 0, 0);
      }
    }
    __syncthreads();   // ds_reads done before next mat's staging overwrites

    // ---- coalesced epilogue: 16-lane groups write 64 consecutive bytes
    #pragma unroll
    for (int ct = 0; ct < 8; ++ct) {
      const int o = ct*16 + l15;
      #pragma unroll
      for (int reg = 0; reg < 4; ++reg)
        Out[pbase[reg] + o] = acc[ct][reg];
    }
  }
}

// ---------------------------------------------------------------------------
// Kernel 2b: per-point kn = mean_c ||Kt[p,c,:]|| (layout [p][d][c]).
// Same per-lane/butterfly summation order as the round-1 inline path.
// Table is 64 KB total (8 KB/batch) -> L1-resident for the logits gather.
// ---------------------------------------------------------------------------
__global__ __launch_bounds__(256) void kn_kernel(const float* __restrict__ Kt,
                                                 float* __restrict__ kn) {
  const int lane = threadIdx.x & 63;
  const int wave = threadIdx.x >> 6;
  const int bn = blockIdx.x * 4 + wave;
  const float* Kp = Kt + (size_t)bn * (CC*3) + 2*lane;
  const float2 kd0 = *(const float2*)Kp;
  const float2 kd1 = *(const float2*)(Kp + CC);
  const float2 kd2 = *(const float2*)(Kp + 2*CC);
  float s = fsqrt(kd0.x*kd0.x + kd1.x*kd1.x + kd2.x*kd2.x)
          + fsqrt(kd0.y*kd0.y + kd1.y*kd1.y + kd2.y*kd2.y);
  #pragma unroll
  for (int off = 1; off < 64; off <<= 1) s += __shfl_xor(s, off, 64);
  if (lane == 0) kn[bn] = s * (1.0f/128.0f);
}

// ---------------------------------------------------------------------------
// Kernel 3a: attention LOGITS pass — wave-per-point, zero barriers.
// K gathers are L2-resident (3 MB/batch per XCD). kn gathered from the
// L1-resident table (drops 32 sqrts + half the reduce-scatter tree).
// Layout [p][d][c]: per-lane loads are three 512B-contiguous float2s.
// ---------------------------------------------------------------------------
__global__ __launch_bounds__(256) void attn_logits_kernel(
    const float* __restrict__ x, const int* __restrict__ idx,
    const float* __restrict__ Q, const float* __restrict__ Kt,
    const float* __restrict__ kn,
    const float* __restrict__ W1, const float* __restrict__ b1,
    const float* __restrict__ W2, const float* __restrict__ b2,
    const float* __restrict__ W3, const float* __restrict__ b3,
    float* __restrict__ warr)
{
  const int lane = threadIdx.x & 63;
  const int wv   = threadIdx.x >> 6;
  // XCD swizzle: batch = blockIdx%8 (all 4 waves of a block share a batch)
  const int bn = ((blockIdx.x & 7) << 11) | (((blockIdx.x >> 3) << 2) | wv);
  const int b = bn >> 11;

  const float* Qp = Q + (size_t)bn * (CC*3) + 2*lane;
  const float2 qd0 = *(const float2*)Qp;
  const float2 qd1 = *(const float2*)(Qp + CC);
  const float2 qd2 = *(const float2*)(Qp + 2*CC);

  const int* ip = idx + (size_t)bn * KNB;
  int j[KNB];
  #pragma unroll
  for (int t = 0; t < KNB; ++t) j[t] = ip[t];

  // per-lane neighbor (kk = lane&15); issue dist/kn gathers EARLY
  const int kk = lane & 15;
  int jsel = j[0];
  #pragma unroll
  for (int t = 1; t < KNB; ++t) jsel = (kk == t) ? j[t] : jsel;

  const float xi0 = x[(size_t)bn*3+0], xi1 = x[(size_t)bn*3+1], xi2 = x[(size_t)bn*3+2];
  const float* xj = x + (size_t)(b*NN + jsel)*3;
  const float xj0 = xj[0], xj1 = xj[1], xj2 = xj[2];
  const float s1 = kn[(size_t)b*NN + jsel];          // L1-resident table

  // K gather + dot partials (same FP order as before: c0 d0,d1,d2 then c1)
  float dpart[KNB];
  #pragma unroll
  for (int t = 0; t < KNB; ++t) {
    const float* Kp = Kt + (size_t)(b*NN + j[t]) * (CC*3) + 2*lane;
    const float2 kd0 = *(const float2*)Kp;
    const float2 kd1 = *(const float2*)(Kp + CC);
    const float2 kd2 = *(const float2*)(Kp + 2*CC);
    dpart[t] = qd0.x*kd0.x + qd1.x*kd1.x + qd2.x*kd2.x
             + qd0.y*kd0.y + qd1.y*kd1.y + qd2.y*kd2.y;
  }
  float qnp = fsqrt(qd0.x*qd0.x + qd1.x*qd1.x + qd2.x*qd2.x)
            + fsqrt(qd0.y*qd0.y + qd1.y*qd1.y + qd2.y*qd2.y);

  // qn: full 64-lane butterfly (needed on every lane)
  #pragma unroll
  for (int off = 1; off < 64; off <<= 1) qnp += __shfl_xor(qnp, off, 64);
  const float s0 = qnp * (1.0f/128.0f);

  // single-payload reduce-scatter: halve payloads at xor 1/2/4/8 against the
  // lane bit; each lane lands its kk's sum; xor 16/32 complete 64 lanes.
  float d8[8];
  {
    const bool hb = (lane & 1) != 0;
    #pragma unroll
    for (int t = 0; t < 8; ++t) {
      const float keep = hb ? dpart[2*t+1] : dpart[2*t];
      const float send = hb ? dpart[2*t]   : dpart[2*t+1];
      d8[t] = keep + __shfl_xor(send, 1, 64);
    }
  }
  float d4[4];
  {
    const bool hb = (lane & 2) != 0;
    #pragma unroll
    for (int t = 0; t < 4; ++t) {
      const float keep = hb ? d8[2*t+1] : d8[2*t];
      const float send = hb ? d8[2*t]   : d8[2*t+1];
      d4[t] = keep + __shfl_xor(send, 2, 64);
    }
  }
  float d2[2];
  {
    const bool hb = (lane & 4) != 0;
    #pragma unroll
    for (int t = 0; t < 2; ++t) {
      const float keep = hb ? d4[2*t+1] : d4[2*t];
      const float send = hb ? d4[2*t]   : d4[2*t+1];
      d2[t] = keep + __shfl_xor(send, 4, 64);
    }
  }
  float dsel;
  {
    const bool hb = (lane & 8) != 0;
    const float keep = hb ? d2[1] : d2[0];
    const float send = hb ? d2[0] : d2[1];
    dsel = keep + __shfl_xor(send, 8, 64);
  }
  dsel += __shfl_xor(dsel, 16, 64);
  dsel += __shfl_xor(dsel, 32, 64);

  // dist feature
  const float dx = xi0 - xj0, dy = xi1 - xj1, dz = xi2 - xj2;
  const float s3 = fsqrt(dx*dx + dy*dy + dz*dz);
  const float s2 = dsel * (1.0f/128.0f);

  // ---- edge MLP, h-split across the 4 redundant lane groups (g = lane>>4).
  const int g = lane >> 4;
  const int o0 = g*8, o1 = (g^1)*8, o2 = (g^2)*8, o3 = (g^3)*8;

  float h1o[8];
  {
    const float4 b1a = *(const float4*)(b1 + o0);
    const float4 b1b = *(const float4*)(b1 + o0 + 4);
    const float bb1[8] = {b1a.x,b1a.y,b1a.z,b1a.w,b1b.x,b1b.y,b1b.z,b1b.w};
    #pragma unroll
    for (int jj = 0; jj < 8; ++jj) {
      const float4 w = *(const float4*)(W1 + (o0 + jj)*4);
      float u = bb1[jj];
      u = fmaf(w.x, s0, u); u = fmaf(w.y, s1, u);
      u = fmaf(w.z, s2, u); u = fmaf(w.w, s3, u);
      h1o[jj] = silu_f(u);
    }
  }
  float hx16[8], hx32[8], hx48[8];
  #pragma unroll
  for (int jj = 0; jj < 8; ++jj) hx16[jj] = __shfl_xor(h1o[jj], 16, 64);
  #pragma unroll
  for (int jj = 0; jj < 8; ++jj) hx32[jj] = __shfl_xor(h1o[jj], 32, 64);
  #pragma unroll
  for (int jj = 0; jj < 8; ++jj) hx48[jj] = __shfl_xor(hx16[jj], 32, 64);

  float logit;
  {
    const float4 b2a = *(const float4*)(b2 + o0);
    const float4 b2b = *(const float4*)(b2 + o0 + 4);
    const float bb2[8] = {b2a.x,b2a.y,b2a.z,b2a.w,b2b.x,b2b.y,b2b.z,b2b.w};
    const float4 w3a = *(const float4*)(W3 + o0);
    const float4 w3b = *(const float4*)(W3 + o0 + 4);
    const float ww3[8] = {w3a.x,w3a.y,w3a.z,w3a.w,w3b.x,w3b.y,w3b.z,w3b.w};
    float lp = 0.f;
    #pragma unroll
    for (int hh = 0; hh < 8; ++hh) {
      const float* wr = W2 + (o0 + hh)*32;    // row h = g*8+hh
      float a = bb2[hh];
      a += dot8(wr + o0, h1o);
      a += dot8(wr + o1, hx16);
      a += dot8(wr + o2, hx32);
      a += dot8(wr + o3, hx48);
      lp = fmaf(ww3[hh], silu_f(a), lp);
    }
    lp += __shfl_xor(lp, 16, 64);
    lp += __shfl_xor(lp, 32, 64);
    logit = lp + b3[0];
  }
  logit = fminf(fmaxf(logit, -10.0f), 10.0f);

  // softmax over the 16-lane group
  float mx = logit;
  #pragma unroll
  for (int off = 8; off > 0; off >>= 1) mx = fmaxf(mx, __shfl_xor(mx, off, 16));
  const float e = __builtin_amdgcn_exp2f(1.442695040888963f * (logit - mx));
  float ssum = e;
  #pragma unroll
  for (int off = 8; off > 0; off >>= 1) ssum += __shfl_xor(ssum, off, 16);
  const float w = e * frcp(ssum);

  // groups hold identical w for kk=lane&15; lanes 0..15 write the 16 weights
  if (lane < KNB) warr[(size_t)bn * KNB + lane] = w;
}

// ---------------------------------------------------------------------------
// Kernel 3b: attention MESSAGE pass — wave-per-point. U gathers L2-resident;
// message + residual + VN layer norm + clamp + store ([p][c][d] external
// output layout preserved).
// ---------------------------------------------------------------------------
__global__ __launch_bounds__(256) void attn_msg_kernel(
    const int* __restrict__ idx, const float* __restrict__ Q,
    const float* __restrict__ U, const float* __restrict__ warr,
    const float* __restrict__ gam, const float* __restrict__ bet,
    float* __restrict__ out)
{
  const int lane = threadIdx.x & 63;
  const int wv   = threadIdx.x >> 6;
  const int bn = ((blockIdx.x & 7) << 11) | (((blockIdx.x >> 3) << 2) | wv);
  const int b = bn >> 11;

  const float* Qp = Q + (size_t)bn * (CC*3) + 2*lane;
  const float2 qd0 = *(const float2*)Qp;
  const float2 qd1 = *(const float2*)(Qp + CC);
  const float2 qd2 = *(const float2*)(Qp + 2*CC);

  const int* ip = idx + (size_t)bn * KNB;
  int j[KNB];
  #pragma unroll
  for (int t = 0; t < KNB; ++t) j[t] = ip[t];

  const float* wp = warr + (size_t)bn * KNB;
  float wk[KNB];
  #pragma unroll
  for (int t = 0; t < KNB; ++t) wk[t] = wp[t];

  // message: gather U rows, accumulate in t order (same FP order as before)
  float m0=0.f,m1=0.f,m2=0.f,m3=0.f,m4=0.f,m5=0.f;
  #pragma unroll
  for (int t = 0; t < KNB; ++t) {
    const float* Up = U + (size_t)(b*NN + j[t]) * (CC*3) + 2*lane;
    const float2 ud0 = *(const float2*)Up;
    const float2 ud1 = *(const float2*)(Up + CC);
    const float2 ud2 = *(const float2*)(Up + 2*CC);
    const float ww = wk[t];
    m0 = fmaf(ww, ud0.x, m0); m1 = fmaf(ww, ud1.x, m1); m2 = fmaf(ww, ud2.x, m2);
    m3 = fmaf(ww, ud0.y, m3); m4 = fmaf(ww, ud1.y, m4); m5 = fmaf(ww, ud2.y, m5);
  }
  const float oa0 = qd0.x + 0.5f*m0, oa1 = qd1.x + 0.5f*m1, oa2 = qd2.x + 0.5f*m2;
  const float ob0 = qd0.y + 0.5f*m3, ob1 = qd1.y + 0.5f*m4, ob2 = qd2.y + 0.5f*m5;

  // VN layer norm (two channels per lane)
  const float na = fmaxf(fsqrt(oa0*oa0 + oa1*oa1 + oa2*oa2), 1e-6f);
  const float nb = fmaxf(fsqrt(ob0*ob0 + ob1*ob1 + ob2*ob2), 1e-6f);
  float s = na + nb;
  #pragma unroll
  for (int off = 1; off < 64; off <<= 1) s += __shfl_xor(s, off, 64);
  const float mean = s * (1.0f/128.0f);
  const float dva = na - mean, dvb = nb - mean;
  float s2v = dva*dva + dvb*dvb;
  #pragma unroll
  for (int off = 1; off < 64; off <<= 1) s2v += __shfl_xor(s2v, off, 64);
  const float stdv = fmaxf(fsqrt(s2v * (1.0f/127.0f)), 1e-6f);
  const float rstd = frcp(stdv);

  const float2 gm = *(const float2*)(gam + lane*2);
  const float2 bt = *(const float2*)(bet + lane*2);
  const float nsa = (na - mean) * rstd * gm.x + bt.x;
  const float nsb = (nb - mean) * rstd * gm.y + bt.y;
  const float sca = fmaxf(nsa, 1e-6f) * frcp(na);
  const float scb = fmaxf(nsb, 1e-6f) * frcp(nb);
  float fa0 = oa0*sca, fa1 = oa1*sca, fa2 = oa2*sca;
  float fb0 = ob0*scb, fb1 = ob1*scb, fb2 = ob2*scb;
  const float n2a = fmaxf(fsqrt(fa0*fa0 + fa1*fa1 + fa2*fa2), 1e-6f);
  const float n2b = fmaxf(fsqrt(fb0*fb0 + fb1*fb1 + fb2*fb2), 1e-6f);
  const float c2a = fminf(50.0f * frcp(n2a), 1.0f);
  const float c2b = fminf(50.0f * frcp(n2b), 1.0f);

  float* op = out + (size_t)bn * (CC*3) + lane*6;
  floatx4u o4; o4.x = fa0*c2a; o4.y = fa1*c2a; o4.z = fa2*c2a; o4.w = fb0*c2b;
  *(floatx4u*)op = o4;
  *(float2*)(op+4) = make_float2(fb1*c2b, fb2*c2b);
}

// ---------------------------------------------------------------------------
extern "C" void kernel_launch(void* const* d_in, const int* in_sizes, int n_in,
                              void* d_out, int out_size, void* d_ws, size_t ws_size,
                              hipStream_t stream) {
  (void)in_sizes; (void)n_in; (void)out_size; (void)ws_size;
  const float* x   = (const float*)d_in[0];
  const float* v   = (const float*)d_in[1];
  const float* Wq  = (const float*)d_in[2];
  const float* Wk  = (const float*)d_in[3];
  const float* Wu  = (const float*)d_in[4];
  const float* W1  = (const float*)d_in[5];
  const float* b1  = (const float*)d_in[6];
  const float* W2  = (const float*)d_in[7];
  const float* b2  = (const float*)d_in[8];
  const float* W3  = (const float*)d_in[9];
  const float* b3  = (const float*)d_in[10];
  const float* gam = (const float*)d_in[11];
  const float* bet = (const float*)d_in[12];
  float* out = (float*)d_out;

  char* ws = (char*)d_ws;
  int*   idx = (int*)ws;                                  // BN*16 ints (1 MB)
  float* Q   = (float*)(ws + (size_t)BN * KNB * 4);       // BN*384 floats
  float* Kt  = Q  + (size_t)BN * CC * 3;
  float* U   = Kt + (size_t)BN * CC * 3;
  unsigned short* Whl = (unsigned short*)(U + (size_t)BN * CC * 3);  // 3*2*128*128 bf16
  float* warr = (float*)((char*)Whl + (size_t)3 * 2 * CC * CC * 2);  // BN*16 floats (1 MB)
  double* sqd = (double*)(warr + (size_t)BN * KNB);       // BN doubles (128 KB)
  float*  kn  = (float*)(sqd + (size_t)BN);               // BN floats (64 KB)

  sq_kernel<<<BN/256, 256, 0, stream>>>(x, sqd);
  knn_kernel<<<BN/4, 256, 0, stream>>>(x, sqd, idx);
  wconv_kernel<<<192, 256, 0, stream>>>(Wq, Wk, Wu, Whl);
  vn_gemm_mfma<<<(BN*3)/64, 256, 0, stream>>>(v, Whl, Q, Kt, U);
  kn_kernel<<<BN/4, 256, 0, stream>>>(Kt, kn);
  attn_logits_kernel<<<BN/4, 256, 0, stream>>>(x, idx, Q, Kt, kn,
                                               W1, b1, W2, b2, W3, b3, warr);
  attn_msg_kernel<<<BN/4, 256, 0, stream>>>(idx, Q, U, warr, gam, bet, out);
}

// Round 5
// 282.648 us; speedup vs baseline: 1.0005x; 1.0005x over previous
//
#include <hip/hip_runtime.h>
#include <math.h>

#define BB 8
#define NN 2048
#define CC 128
#define KNB 16
#define BN (BB*NN)
#define WPAD 136       // LDS row pad for W (16B-aligned rows, 2-way banks only)

#define EMPTYK 0xFFFFFFFFFFFFFFFFULL

typedef __attribute__((ext_vector_type(8))) short short8;
typedef __attribute__((ext_vector_type(4))) float floatx4;
typedef __attribute__((ext_vector_type(4), aligned(4))) float floatx4u;  // 4B-aligned float4

// fast silu: x / (1 + e^-x) via v_exp_f32 + v_rcp_f32 (~1 ulp, plenty here)
__device__ __forceinline__ float silu_f(float x) {
  const float e = __builtin_amdgcn_exp2f(-1.442695040888963f * x);
  return x * __builtin_amdgcn_rcpf(1.0f + e);
}
__device__ __forceinline__ float fsqrt(float x) { return __builtin_amdgcn_sqrtf(x); }
__device__ __forceinline__ float frcp(float x)  { return __builtin_amdgcn_rcpf(x); }

__device__ __forceinline__ unsigned long long umin64(unsigned long long a, unsigned long long b) {
  return (b < a) ? b : a;
}

__device__ __forceinline__ unsigned short f2bf(float f) {   // RNE
  unsigned u = __float_as_uint(f);
  unsigned r = u + 0x7FFFu + ((u >> 16) & 1u);
  return (unsigned short)(r >> 16);
}
__device__ __forceinline__ float bf2f(unsigned short s) {
  return __uint_as_float(((unsigned)s) << 16);
}

// 8-wide dot: 2 float4 loads (L1-resident weights) + 8 FMA
__device__ __forceinline__ float dot8(const float* __restrict__ w, const float* __restrict__ h) {
  const float4 a = *(const float4*)w;
  const float4 b = *(const float4*)(w + 4);
  float s = a.x*h[0];
  s = fmaf(a.y, h[1], s); s = fmaf(a.z, h[2], s); s = fmaf(a.w, h[3], s);
  s = fmaf(b.x, h[4], s); s = fmaf(b.y, h[5], s); s = fmaf(b.z, h[6], s);
  s = fmaf(b.w, h[7], s);
  return s;
}

// ---------------------------------------------------------------------------
// Kernel 0: per-point f64 squared-norm (bitwise-identical expression to the
// old in-loop computation) + packed float4 (x,y,z,0) position table so the
// knn distance loop does 2 VMEM/pair instead of 4.
// ---------------------------------------------------------------------------
__global__ __launch_bounds__(256) void sq_kernel(const float* __restrict__ x,
                                                 double* __restrict__ sqd,
                                                 float4* __restrict__ x4) {
  const int i = blockIdx.x*256 + threadIdx.x;      // 0..BN-1
  const float f0 = x[i*3+0], f1 = x[i*3+1], f2 = x[i*3+2];
  const double a0 = (double)f0, a1 = (double)f1, a2 = (double)f2;
  sqd[i] = a0*a0 + a1*a1 + a2*a2;
  x4[i] = make_float4(f0, f1, f2, 0.0f);
}

// ---------------------------------------------------------------------------
// Kernel 1: kNN — one WAVE per query, 4 waves/block, no LDS, no barriers.
// Distance loop: packed x4 + precomputed f64 sq table (values bitwise
// identical to computing inline). Selection: u32 high-word butterfly +
// ballot/readlane, exact low-word fallback on ties (ordering identical to
// the u64 butterfly; key = f64-bits | index, index unique).
// ---------------------------------------------------------------------------
__global__ __launch_bounds__(256) void knn_kernel(const float4* __restrict__ x4,
                                                  const double* __restrict__ sqd,
                                                  int* __restrict__ idx) {
  const int lane = threadIdx.x & 63;
  const int wave = threadIdx.x >> 6;
  const int bn = blockIdx.x * 4 + wave;
  const int b = bn >> 11;
  const int n = bn & (NN - 1);

  const float4* xb4 = x4 + (size_t)b * NN;
  const double* sqb = sqd + (size_t)b * NN;
  const float4 xq = xb4[n];
  const double xn0 = (double)xq.x, xn1 = (double)xq.y, xn2 = (double)xq.z;
  const double sqn = sqb[n];

  unsigned long long k[32];
  unsigned long long t0 = EMPTYK, t1 = EMPTYK, t2 = EMPTYK, t3 = EMPTYK;

  #pragma unroll
  for (int i = 0; i < 32; ++i) {
    const int m = i*64 + lane;
    const float4 xm = xb4[m];
    const double a0 = (double)xm.x, a1 = (double)xm.y, a2 = (double)xm.z;
    const double sqm = sqb[m];
    const double dot = xn0*a0 + xn1*a1 + xn2*a2;
    const double d = sqn + sqm - 2.0*dot;
    unsigned long long kk =
        ((unsigned long long)__double_as_longlong(d) & ~2047ULL) | (unsigned long long)m;
    if (m == n) kk = 0x8000000000000000ULL | (unsigned long long)m;
    k[i] = kk;
    const bool l3 = kk < t3, l2 = kk < t2, l1 = kk < t1, l0 = kk < t0;
    t3 = l3 ? (l2 ? t2 : kk) : t3;
    t2 = l2 ? (l1 ? t1 : kk) : t2;
    t1 = l1 ? (l0 ? t0 : kk) : t1;
    t0 = l0 ? kk : t0;
  }

  int* op = idx + (size_t)bn * KNB;
  for (int t = 0; t < KNB; ++t) {
    const unsigned h0 = (unsigned)(t0 >> 32);
    const unsigned l0w = (unsigned)t0;
    unsigned hm = h0;
    #pragma unroll
    for (int off = 32; off > 0; off >>= 1) {
      const unsigned o = (unsigned)__shfl_xor((int)hm, off, 64);
      hm = (o < hm) ? o : hm;
    }
    const bool tied = (h0 == hm);
    const unsigned long long bal = __ballot(tied);
    unsigned lm;
    if (__builtin_popcountll(bal) == 1) {
      const int owner = __builtin_ctzll(bal);
      lm = (unsigned)__shfl((int)l0w, owner, 64);
    } else {
      lm = tied ? l0w : 0xFFFFFFFFu;
      #pragma unroll
      for (int off = 32; off > 0; off >>= 1) {
        const unsigned o = (unsigned)__shfl_xor((int)lm, off, 64);
        lm = (o < lm) ? o : lm;
      }
    }
    const unsigned long long g = ((unsigned long long)hm << 32) | (unsigned long long)lm;

    if (lane == 0) op[t] = (int)(lm & 2047u);

    const bool own = tied && (l0w == lm);
    t0 = own ? t1 : t0;
    t1 = own ? t2 : t1;
    t2 = own ? t3 : t2;
    t3 = own ? EMPTYK : t3;

    const bool need = (t0 == EMPTYK);
    if (__any(need)) {
      unsigned long long nm = EMPTYK;
      #pragma unroll
      for (int i = 0; i < 32; ++i) {
        const unsigned long long c = (k[i] > g) ? k[i] : EMPTYK;
        nm = umin64(nm, c);
      }
      t0 = need ? nm : t0;
    }
  }
}

// ---------------------------------------------------------------------------
// Kernel 1b: W pre-conversion — f32 -> bf16 hi/lo planes, once per matrix.
// ---------------------------------------------------------------------------
__global__ __launch_bounds__(256) void wconv_kernel(
    const float* __restrict__ Wq, const float* __restrict__ Wk, const float* __restrict__ Wu,
    unsigned short* __restrict__ Whl)
{
  const int i = blockIdx.x*256 + threadIdx.x;      // 0..49151
  const int mat = i >> 14, rem = i & 16383;
  const float* W = (mat == 0) ? Wq : ((mat == 1) ? Wk : Wu);
  const float f = W[rem];
  const unsigned short h = f2bf(f);
  const float r = f - bf2f(h);
  unsigned short* base = Whl + (size_t)mat * 2 * CC * CC;
  base[rem]           = h;
  base[CC*CC + rem]   = f2bf(r);
}

// ---------------------------------------------------------------------------
// Kernel 2: Q/K/U via bf16 split-precision MFMA, all three matrices per
// block (A-tile loaded+converted once; v HBM read 1x). R3 configuration:
// both hi/lo planes in LDS, [p][c][d] gather-friendly output layout.
// ---------------------------------------------------------------------------
__global__ __launch_bounds__(256, 2) void vn_gemm_mfma(
    const float* __restrict__ v, const unsigned short* __restrict__ Whl,
    float* __restrict__ Q, float* __restrict__ Kt, float* __restrict__ U)
{
  __shared__ short Wh[CC][WPAD];
  __shared__ short Wl[CC][WPAD];

  const int tid  = threadIdx.x;
  const int lane = tid & 63;
  const int wave = tid >> 6;
  const int quad = lane >> 4;
  const int l15  = lane & 15;

  const int m = blockIdx.x*64 + wave*16 + l15;
  const int p = m / 3, d = m - 3*p;
  const float* vb = v + (size_t)p * (CC*3) + d;
  float areg[32];
  #pragma unroll
  for (int kc = 0; kc < 4; ++kc)
    #pragma unroll
    for (int j = 0; j < 8; ++j)
      areg[kc*8+j] = vb[(kc*32 + quad*8 + j)*3];

  short8 ah[4], al[4];
  #pragma unroll
  for (int kc = 0; kc < 4; ++kc)
    #pragma unroll
    for (int j = 0; j < 8; ++j) {
      const float f = areg[kc*8+j];
      unsigned short h = f2bf(f);
      float r = f - bf2f(h);
      ah[kc][j] = (short)h;
      al[kc][j] = (short)f2bf(r);
    }

  const int r0s = blockIdx.x*64 + wave*16 + quad*4;
  int pbase[4];
  #pragma unroll
  for (int reg = 0; reg < 4; ++reg) {
    const int r = r0s + reg;
    const int pp = r / 3;
    pbase[reg] = pp * (CC*3) + (r - 3*pp);
  }
  const int l153 = l15 * 3;

  for (int mat = 0; mat < 3; ++mat) {
    float* __restrict__ Out = (mat == 0) ? Q : ((mat == 1) ? Kt : U);
    const unsigned short* Wg = Whl + (size_t)mat * 2 * CC * CC;

    #pragma unroll
    for (int it = 0; it < 8; ++it) {
      const int i = it*256 + tid;          // 2048 short8 chunks per plane
      const int o = i >> 4, c8 = (i & 15) * 8;
      *(short8*)&Wh[o][c8] = *(const short8*)&Wg[o*CC + c8];
      *(short8*)&Wl[o][c8] = *(const short8*)&Wg[CC*CC + o*CC + c8];
    }
    __syncthreads();

    floatx4 acc[8];
    #pragma unroll
    for (int ct = 0; ct < 8; ++ct) acc[ct] = (floatx4){0.f, 0.f, 0.f, 0.f};

    #pragma unroll
    for (int kc = 0; kc < 4; ++kc) {
      #pragma unroll
      for (int ct = 0; ct < 8; ++ct) {
        const int o = ct*16 + l15;
        const short8 bh = *(const short8*)&Wh[o][kc*32 + quad*8];
        const short8 bl = *(const short8*)&Wl[o][kc*32 + quad*8];
        acc[ct] = __builtin_amdgcn_mfma_f32_16x16x32_bf16(ah[kc], bh, acc[ct], 0, 0, 0);
        acc[ct] = __builtin_amdgcn_mfma_f32_16x16x32_bf16(al[kc], bh, acc[ct], 0, 0, 0);
        acc[ct] = __builtin_amdgcn_mfma_f32_16x16x32_bf16(ah[kc], bl, acc[ct], 0, 0, 0);
      }
    }
    __syncthreads();   // all waves' ds_reads done before next stage overwrites

    #pragma unroll
    for (int ct = 0; ct < 8; ++ct) {
      const int o3 = ct*48 + l153;
      #pragma unroll
      for (int reg = 0; reg < 4; ++reg)
        Out[pbase[reg] + o3] = acc[ct][reg];
    }
  }
}

// ---------------------------------------------------------------------------
// Kernel 2b: per-point kn = mean_c ||Kt[p,c,:]|| on the [p][c][d] layout.
// Per-lane partial and xor-pair summation order are bitwise-identical to
// the inline logits path it replaces. 64 KB table -> L1-resident gathers.
// ---------------------------------------------------------------------------
__global__ __launch_bounds__(256) void kn_kernel(const float* __restrict__ Kt,
                                                 float* __restrict__ kn) {
  const int lane = threadIdx.x & 63;
  const int wave = threadIdx.x >> 6;
  const int bn = blockIdx.x * 4 + wave;
  const float* Kp = Kt + (size_t)bn * (CC*3) + lane*6;
  const floatx4u kv = *(const floatx4u*)Kp;
  const float2 kw = *(const float2*)(Kp+4);
  float s = fsqrt(kv.x*kv.x + kv.y*kv.y + kv.z*kv.z)
          + fsqrt(kv.w*kv.w + kw.x*kw.x + kw.y*kw.y);
  #pragma unroll
  for (int off = 1; off < 64; off <<= 1) s += __shfl_xor(s, off, 64);
  if (lane == 0) kn[bn] = s * (1.0f/128.0f);
}

// ---------------------------------------------------------------------------
// Kernel 3a: attention LOGITS pass — wave-per-point, zero barriers.
// K gathers L2-resident (3 MB/batch per XCD); [p][c][d] layout -> 2 loads
// per gathered row (float4+float2, 24B contiguous per lane). kn from the
// L1-resident table -> 32 fewer sqrts + single-payload reduce-scatter.
// ---------------------------------------------------------------------------
__global__ __launch_bounds__(256) void attn_logits_kernel(
    const float* __restrict__ x, const int* __restrict__ idx,
    const float* __restrict__ Q, const float* __restrict__ Kt,
    const float* __restrict__ kn,
    const float* __restrict__ W1, const float* __restrict__ b1,
    const float* __restrict__ W2, const float* __restrict__ b2,
    const float* __restrict__ W3, const float* __restrict__ b3,
    float* __restrict__ warr)
{
  const int lane = threadIdx.x & 63;
  const int wv   = threadIdx.x >> 6;
  // XCD swizzle: batch = blockIdx%8 (all 4 waves of a block share a batch)
  const int bn = ((blockIdx.x & 7) << 11) | (((blockIdx.x >> 3) << 2) | wv);
  const int b = bn >> 11;

  const float* Qp = Q + (size_t)bn * (CC*3) + lane*6;
  const floatx4u q0 = *(const floatx4u*)Qp;
  const float2 q1 = *(const float2*)(Qp+4);
  const float2 qa = make_float2(q0.x, q0.y);
  const float2 qb = make_float2(q0.z, q0.w);
  const float2 qc = make_float2(q1.x, q1.y);

  const int* ip = idx + (size_t)bn * KNB;
  int j[KNB];
  #pragma unroll
  for (int t = 0; t < KNB; ++t) j[t] = ip[t];

  // per-lane neighbor (kk = lane&15); issue dist/kn gathers EARLY
  const int kk = lane & 15;
  int jsel = j[0];
  #pragma unroll
  for (int t = 1; t < KNB; ++t) jsel = (kk == t) ? j[t] : jsel;

  const float xi0 = x[(size_t)bn*3+0], xi1 = x[(size_t)bn*3+1], xi2 = x[(size_t)bn*3+2];
  const float* xj = x + (size_t)(b*NN + jsel)*3;
  const float xj0 = xj[0], xj1 = xj[1], xj2 = xj[2];
  const float s1 = kn[(size_t)b*NN + jsel];          // L1-resident table

  // K gather + dot partials (same FP order as always)
  float dpart[KNB];
  #pragma unroll
  for (int t = 0; t < KNB; ++t) {
    const float* Kp = Kt + (size_t)(b*NN + j[t]) * (CC*3) + lane*6;
    const floatx4u kv = *(const floatx4u*)Kp;
    const float2 kw = *(const float2*)(Kp+4);
    dpart[t] = qa.x*kv.x + qa.y*kv.y + qb.x*kv.z + qb.y*kv.w + qc.x*kw.x + qc.y*kw.y;
  }
  float qnp = fsqrt(qa.x*qa.x + qa.y*qa.y + qb.x*qb.x) + fsqrt(qb.y*qb.y + qc.x*qc.x + qc.y*qc.y);

  // qn: full 64-lane butterfly (needed on every lane)
  #pragma unroll
  for (int off = 1; off < 64; off <<= 1) qnp += __shfl_xor(qnp, off, 64);
  const float s0 = qnp * (1.0f/128.0f);

  // single-payload reduce-scatter: halve payloads at xor 1/2/4/8 against the
  // lane bit; each lane lands its kk's sum; xor 16/32 complete 64 lanes.
  float d8[8];
  {
    const bool hb = (lane & 1) != 0;
    #pragma unroll
    for (int t = 0; t < 8; ++t) {
      const float keep = hb ? dpart[2*t+1] : dpart[2*t];
      const float send = hb ? dpart[2*t]   : dpart[2*t+1];
      d8[t] = keep + __shfl_xor(send, 1, 64);
    }
  }
  float d4[4];
  {
    const bool hb = (lane & 2) != 0;
    #pragma unroll
    for (int t = 0; t < 4; ++t) {
      const float keep = hb ? d8[2*t+1] : d8[2*t];
      const float send = hb ? d8[2*t]   : d8[2*t+1];
      d4[t] = keep + __shfl_xor(send, 2, 64);
    }
  }
  float d2[2];
  {
    const bool hb = (lane & 4) != 0;
    #pragma unroll
    for (int t = 0; t < 2; ++t) {
      const float keep = hb ? d4[2*t+1] : d4[2*t];
      const float send = hb ? d4[2*t]   : d4[2*t+1];
      d2[t] = keep + __shfl_xor(send, 4, 64);
    }
  }
  float dsel;
  {
    const bool hb = (lane & 8) != 0;
    const float keep = hb ? d2[1] : d2[0];
    const float send = hb ? d2[0] : d2[1];
    dsel = keep + __shfl_xor(send, 8, 64);
  }
  dsel += __shfl_xor(dsel, 16, 64);
  dsel += __shfl_xor(dsel, 32, 64);

  // dist feature
  const float dx = xi0 - xj0, dy = xi1 - xj1, dz = xi2 - xj2;
  const float s3 = fsqrt(dx*dx + dy*dy + dz*dz);
  const float s2 = dsel * (1.0f/128.0f);

  // ---- edge MLP, h-split across the 4 redundant lane groups (g = lane>>4).
  const int g = lane >> 4;
  const int o0 = g*8, o1 = (g^1)*8, o2 = (g^2)*8, o3 = (g^3)*8;

  float h1o[8];
  {
    const float4 b1a = *(const float4*)(b1 + o0);
    const float4 b1b = *(const float4*)(b1 + o0 + 4);
    const float bb1[8] = {b1a.x,b1a.y,b1a.z,b1a.w,b1b.x,b1b.y,b1b.z,b1b.w};
    #pragma unroll
    for (int jj = 0; jj < 8; ++jj) {
      const float4 w = *(const float4*)(W1 + (o0 + jj)*4);
      float u = bb1[jj];
      u = fmaf(w.x, s0, u); u = fmaf(w.y, s1, u);
      u = fmaf(w.z, s2, u); u = fmaf(w.w, s3, u);
      h1o[jj] = silu_f(u);
    }
  }
  float hx16[8], hx32[8], hx48[8];
  #pragma unroll
  for (int jj = 0; jj < 8; ++jj) hx16[jj] = __shfl_xor(h1o[jj], 16, 64);
  #pragma unroll
  for (int jj = 0; jj < 8; ++jj) hx32[jj] = __shfl_xor(h1o[jj], 32, 64);
  #pragma unroll
  for (int jj = 0; jj < 8; ++jj) hx48[jj] = __shfl_xor(hx16[jj], 32, 64);

  float logit;
  {
    const float4 b2a = *(const float4*)(b2 + o0);
    const float4 b2b = *(const float4*)(b2 + o0 + 4);
    const float bb2[8] = {b2a.x,b2a.y,b2a.z,b2a.w,b2b.x,b2b.y,b2b.z,b2b.w};
    const float4 w3a = *(const float4*)(W3 + o0);
    const float4 w3b = *(const float4*)(W3 + o0 + 4);
    const float ww3[8] = {w3a.x,w3a.y,w3a.z,w3a.w,w3b.x,w3b.y,w3b.z,w3b.w};
    float lp = 0.f;
    #pragma unroll
    for (int hh = 0; hh < 8; ++hh) {
      const float* wr = W2 + (o0 + hh)*32;    // row h = g*8+hh
      float a = bb2[hh];
      a += dot8(wr + o0, h1o);
      a += dot8(wr + o1, hx16);
      a += dot8(wr + o2, hx32);
      a += dot8(wr + o3, hx48);
      lp = fmaf(ww3[hh], silu_f(a), lp);
    }
    lp += __shfl_xor(lp, 16, 64);
    lp += __shfl_xor(lp, 32, 64);
    logit = lp + b3[0];
  }
  logit = fminf(fmaxf(logit, -10.0f), 10.0f);

  // softmax over the 16-lane group
  float mx = logit;
  #pragma unroll
  for (int off = 8; off > 0; off >>= 1) mx = fmaxf(mx, __shfl_xor(mx, off, 16));
  const float e = __builtin_amdgcn_exp2f(1.442695040888963f * (logit - mx));
  float ssum = e;
  #pragma unroll
  for (int off = 8; off > 0; off >>= 1) ssum += __shfl_xor(ssum, off, 16);
  const float w = e * frcp(ssum);

  // groups hold identical w for kk=lane&15; lanes 0..15 write the 16 weights
  if (lane < KNB) warr[(size_t)bn * KNB + lane] = w;
}

// ---------------------------------------------------------------------------
// Kernel 3b: attention MESSAGE pass — wave-per-point. U gathers L2-resident
// (3 MB/batch per XCD); message + residual + VN layer norm + clamp + store.
// ---------------------------------------------------------------------------
__global__ __launch_bounds__(256) void attn_msg_kernel(
    const int* __restrict__ idx, const float* __restrict__ Q,
    const float* __restrict__ U, const float* __restrict__ warr,
    const float* __restrict__ gam, const float* __restrict__ bet,
    float* __restrict__ out)
{
  const int lane = threadIdx.x & 63;
  const int wv   = threadIdx.x >> 6;
  const int bn = ((blockIdx.x & 7) << 11) | (((blockIdx.x >> 3) << 2) | wv);
  const int b = bn >> 11;

  // idx first -> U gather addresses resolve ASAP (everything else independent)
  const int* ip = idx + (size_t)bn * KNB;
  int j[KNB];
  #pragma unroll
  for (int t = 0; t < KNB; ++t) j[t] = ip[t];

  const float* Qp = Q + (size_t)bn * (CC*3) + lane*6;
  const floatx4u q0 = *(const floatx4u*)Qp;
  const float2 q1 = *(const float2*)(Qp+4);

  const float* wp = warr + (size_t)bn * KNB;
  float wk[KNB];
  #pragma unroll
  for (int t = 0; t < KNB; ++t) wk[t] = wp[t];

  // message: gather U rows, accumulate in t order (bitwise same as before)
  float m0=0.f,m1=0.f,m2=0.f,m3=0.f,m4=0.f,m5=0.f;
  #pragma unroll
  for (int t = 0; t < KNB; ++t) {
    const float* Up = U + (size_t)(b*NN + j[t]) * (CC*3) + lane*6;
    const floatx4u uv = *(const floatx4u*)Up;
    const float2 uw = *(const float2*)(Up+4);
    const float ww = wk[t];
    m0 = fmaf(ww, uv.x, m0); m1 = fmaf(ww, uv.y, m1); m2 = fmaf(ww, uv.z, m2);
    m3 = fmaf(ww, uv.w, m3); m4 = fmaf(ww, uw.x, m4); m5 = fmaf(ww, uw.y, m5);
  }
  const float oa0 = q0.x + 0.5f*m0, oa1 = q0.y + 0.5f*m1, oa2 = q0.z + 0.5f*m2;
  const float ob0 = q0.w + 0.5f*m3, ob1 = q1.x + 0.5f*m4, ob2 = q1.y + 0.5f*m5;

  // VN layer norm (two channels per lane)
  const float na = fmaxf(fsqrt(oa0*oa0 + oa1*oa1 + oa2*oa2), 1e-6f);
  const float nb = fmaxf(fsqrt(ob0*ob0 + ob1*ob1 + ob2*ob2), 1e-6f);
  float s = na + nb;
  #pragma unroll
  for (int off = 1; off < 64; off <<= 1) s += __shfl_xor(s, off, 64);
  const float mean = s * (1.0f/128.0f);
  const float dva = na - mean, dvb = nb - mean;
  float s2v = dva*dva + dvb*dvb;
  #pragma unroll
  for (int off = 1; off < 64; off <<= 1) s2v += __shfl_xor(s2v, off, 64);
  const float stdv = fmaxf(fsqrt(s2v * (1.0f/127.0f)), 1e-6f);
  const float rstd = frcp(stdv);

  const float2 gm = *(const float2*)(gam + lane*2);
  const float2 bt = *(const float2*)(bet + lane*2);
  const float nsa = (na - mean) * rstd * gm.x + bt.x;
  const float nsb = (nb - mean) * rstd * gm.y + bt.y;
  const float sca = fmaxf(nsa, 1e-6f) * frcp(na);
  const float scb = fmaxf(nsb, 1e-6f) * frcp(nb);
  float fa0 = oa0*sca, fa1 = oa1*sca, fa2 = oa2*sca;
  float fb0 = ob0*scb, fb1 = ob1*scb, fb2 = ob2*scb;
  const float n2a = fmaxf(fsqrt(fa0*fa0 + fa1*fa1 + fa2*fa2), 1e-6f);
  const float n2b = fmaxf(fsqrt(fb0*fb0 + fb1*fb1 + fb2*fb2), 1e-6f);
  const float c2a = fminf(50.0f * frcp(n2a), 1.0f);
  const float c2b = fminf(50.0f * frcp(n2b), 1.0f);

  float* op = out + (size_t)bn * (CC*3) + lane*6;
  floatx4u o4; o4.x = fa0*c2a; o4.y = fa1*c2a; o4.z = fa2*c2a; o4.w = fb0*c2b;
  *(floatx4u*)op = o4;
  *(float2*)(op+4) = make_float2(fb1*c2b, fb2*c2b);
}

// ---------------------------------------------------------------------------
extern "C" void kernel_launch(void* const* d_in, const int* in_sizes, int n_in,
                              void* d_out, int out_size, void* d_ws, size_t ws_size,
                              hipStream_t stream) {
  (void)in_sizes; (void)n_in; (void)out_size; (void)ws_size;
  const float* x   = (const float*)d_in[0];
  const float* v   = (const float*)d_in[1];
  const float* Wq  = (const float*)d_in[2];
  const float* Wk  = (const float*)d_in[3];
  const float* Wu  = (const float*)d_in[4];
  const float* W1  = (const float*)d_in[5];
  const float* b1  = (const float*)d_in[6];
  const float* W2  = (const float*)d_in[7];
  const float* b2  = (const float*)d_in[8];
  const float* W3  = (const float*)d_in[9];
  const float* b3  = (const float*)d_in[10];
  const float* gam = (const float*)d_in[11];
  const float* bet = (const float*)d_in[12];
  float* out = (float*)d_out;

  char* ws = (char*)d_ws;
  int*   idx = (int*)ws;                                  // BN*16 ints (1 MB)
  float* Q   = (float*)(ws + (size_t)BN * KNB * 4);       // BN*384 floats
  float* Kt  = Q  + (size_t)BN * CC * 3;
  float* U   = Kt + (size_t)BN * CC * 3;
  unsigned short* Whl = (unsigned short*)(U + (size_t)BN * CC * 3);  // 3*2*128*128 bf16
  float* warr = (float*)((char*)Whl + (size_t)3 * 2 * CC * CC * 2);  // BN*16 floats (1 MB)
  double* sqd = (double*)(warr + (size_t)BN * KNB);       // BN doubles (128 KB)
  float4* x4  = (float4*)(sqd + (size_t)BN);              // BN float4 (256 KB)
  float*  kn  = (float*)(x4 + (size_t)BN);                // BN floats (64 KB)

  sq_kernel<<<BN/256, 256, 0, stream>>>(x, sqd, x4);
  knn_kernel<<<BN/4, 256, 0, stream>>>(x4, sqd, idx);
  wconv_kernel<<<192, 256, 0, stream>>>(Wq, Wk, Wu, Whl);
  vn_gemm_mfma<<<(BN*3)/64, 256, 0, stream>>>(v, Whl, Q, Kt, U);
  kn_kernel<<<BN/4, 256, 0, stream>>>(Kt, kn);
  attn_logits_kernel<<<BN/4, 256, 0, stream>>>(x, idx, Q, Kt, kn,
                                               W1, b1, W2, b2, W3, b3, warr);
  attn_msg_kernel<<<BN/4, 256, 0, stream>>>(idx, Q, U, warr, gam, bet, out);
}

// Round 6
// 277.672 us; speedup vs baseline: 1.0184x; 1.0179x over previous
//
#include <hip/hip_runtime.h>
#include <math.h>

#define BB 8
#define NN 2048
#define CC 128
#define KNB 16
#define BN (BB*NN)
#define WPAD 136       // LDS row pad for W (16B-aligned rows, 2-way banks only)

#define EMPTYK 0xFFFFFFFFFFFFFFFFULL

typedef __attribute__((ext_vector_type(8))) short short8;
typedef __attribute__((ext_vector_type(4))) float floatx4;
typedef __attribute__((ext_vector_type(4), aligned(4))) float floatx4u;  // 4B-aligned float4

// fast silu: x / (1 + e^-x) via v_exp_f32 + v_rcp_f32 (~1 ulp, plenty here)
__device__ __forceinline__ float silu_f(float x) {
  const float e = __builtin_amdgcn_exp2f(-1.442695040888963f * x);
  return x * __builtin_amdgcn_rcpf(1.0f + e);
}
__device__ __forceinline__ float fsqrt(float x) { return __builtin_amdgcn_sqrtf(x); }
__device__ __forceinline__ float frcp(float x)  { return __builtin_amdgcn_rcpf(x); }

__device__ __forceinline__ unsigned long long umin64(unsigned long long a, unsigned long long b) {
  return (b < a) ? b : a;
}

__device__ __forceinline__ unsigned short f2bf(float f) {   // RNE
  unsigned u = __float_as_uint(f);
  unsigned r = u + 0x7FFFu + ((u >> 16) & 1u);
  return (unsigned short)(r >> 16);
}
__device__ __forceinline__ float bf2f(unsigned short s) {
  return __uint_as_float(((unsigned)s) << 16);
}

// 8-wide dot: 2 float4 loads (L1-resident weights) + 8 FMA
__device__ __forceinline__ float dot8(const float* __restrict__ w, const float* __restrict__ h) {
  const float4 a = *(const float4*)w;
  const float4 b = *(const float4*)(w + 4);
  float s = a.x*h[0];
  s = fmaf(a.y, h[1], s); s = fmaf(a.z, h[2], s); s = fmaf(a.w, h[3], s);
  s = fmaf(b.x, h[4], s); s = fmaf(b.y, h[5], s); s = fmaf(b.z, h[6], s);
  s = fmaf(b.w, h[7], s);
  return s;
}

// ---------------------------------------------------------------------------
// Kernel 0: per-point f64 squared-norm (bitwise-identical expression to the
// old in-loop computation) + packed float4 (x,y,z,0) position table so the
// knn distance loop does 2 VMEM/pair instead of 4.
// ---------------------------------------------------------------------------
__global__ __launch_bounds__(256) void sq_kernel(const float* __restrict__ x,
                                                 double* __restrict__ sqd,
                                                 float4* __restrict__ x4) {
  const int i = blockIdx.x*256 + threadIdx.x;      // 0..BN-1
  const float f0 = x[i*3+0], f1 = x[i*3+1], f2 = x[i*3+2];
  const double a0 = (double)f0, a1 = (double)f1, a2 = (double)f2;
  sqd[i] = a0*a0 + a1*a1 + a2*a2;
  x4[i] = make_float4(f0, f1, f2, 0.0f);
}

// ---------------------------------------------------------------------------
// Kernel 1: kNN — one WAVE per query, 4 waves/block, no LDS, no barriers.
// __launch_bounds__(256, 1): k[32] (64 VGPRs) was being SPILLED TO SCRATCH
// under the default occupancy target (VGPR_Count=52 observed, r5) — every
// main-loop iter did a scratch store and refills read scratch back. The
// relaxed bound keeps the candidate array register-resident.
// ---------------------------------------------------------------------------
__global__ __launch_bounds__(256, 1) void knn_kernel(const float4* __restrict__ x4,
                                                     const double* __restrict__ sqd,
                                                     int* __restrict__ idx) {
  const int lane = threadIdx.x & 63;
  const int wave = threadIdx.x >> 6;
  const int bn = blockIdx.x * 4 + wave;
  const int b = bn >> 11;
  const int n = bn & (NN - 1);

  const float4* xb4 = x4 + (size_t)b * NN;
  const double* sqb = sqd + (size_t)b * NN;
  const float4 xq = xb4[n];
  const double xn0 = (double)xq.x, xn1 = (double)xq.y, xn2 = (double)xq.z;
  const double sqn = sqb[n];

  unsigned long long k[32];
  unsigned long long t0 = EMPTYK, t1 = EMPTYK, t2 = EMPTYK, t3 = EMPTYK;

  #pragma unroll
  for (int i = 0; i < 32; ++i) {
    const int m = i*64 + lane;
    const float4 xm = xb4[m];
    const double a0 = (double)xm.x, a1 = (double)xm.y, a2 = (double)xm.z;
    const double sqm = sqb[m];
    const double dot = xn0*a0 + xn1*a1 + xn2*a2;
    const double d = sqn + sqm - 2.0*dot;
    unsigned long long kk =
        ((unsigned long long)__double_as_longlong(d) & ~2047ULL) | (unsigned long long)m;
    if (m == n) kk = 0x8000000000000000ULL | (unsigned long long)m;
    k[i] = kk;
    const bool l3 = kk < t3, l2 = kk < t2, l1 = kk < t1, l0 = kk < t0;
    t3 = l3 ? (l2 ? t2 : kk) : t3;
    t2 = l2 ? (l1 ? t1 : kk) : t2;
    t1 = l1 ? (l0 ? t0 : kk) : t1;
    t0 = l0 ? kk : t0;
  }

  int* op = idx + (size_t)bn * KNB;
  for (int t = 0; t < KNB; ++t) {
    const unsigned h0 = (unsigned)(t0 >> 32);
    const unsigned l0w = (unsigned)t0;
    unsigned hm = h0;
    #pragma unroll
    for (int off = 32; off > 0; off >>= 1) {
      const unsigned o = (unsigned)__shfl_xor((int)hm, off, 64);
      hm = (o < hm) ? o : hm;
    }
    const bool tied = (h0 == hm);
    const unsigned long long bal = __ballot(tied);
    unsigned lm;
    if (__builtin_popcountll(bal) == 1) {
      const int owner = __builtin_ctzll(bal);
      lm = (unsigned)__shfl((int)l0w, owner, 64);
    } else {
      lm = tied ? l0w : 0xFFFFFFFFu;
      #pragma unroll
      for (int off = 32; off > 0; off >>= 1) {
        const unsigned o = (unsigned)__shfl_xor((int)lm, off, 64);
        lm = (o < lm) ? o : lm;
      }
    }
    const unsigned long long g = ((unsigned long long)hm << 32) | (unsigned long long)lm;

    if (lane == 0) op[t] = (int)(lm & 2047u);

    const bool own = tied && (l0w == lm);
    t0 = own ? t1 : t0;
    t1 = own ? t2 : t1;
    t2 = own ? t3 : t2;
    t3 = own ? EMPTYK : t3;

    const bool need = (t0 == EMPTYK);
    if (__any(need)) {
      unsigned long long nm = EMPTYK;
      #pragma unroll
      for (int i = 0; i < 32; ++i) {
        const unsigned long long c = (k[i] > g) ? k[i] : EMPTYK;
        nm = umin64(nm, c);
      }
      t0 = need ? nm : t0;
    }
  }
}

// ---------------------------------------------------------------------------
// Kernel 1b: W pre-conversion — f32 -> bf16 hi/lo planes, once per matrix.
// ---------------------------------------------------------------------------
__global__ __launch_bounds__(256) void wconv_kernel(
    const float* __restrict__ Wq, const float* __restrict__ Wk, const float* __restrict__ Wu,
    unsigned short* __restrict__ Whl)
{
  const int i = blockIdx.x*256 + threadIdx.x;      // 0..49151
  const int mat = i >> 14, rem = i & 16383;
  const float* W = (mat == 0) ? Wq : ((mat == 1) ? Wk : Wu);
  const float f = W[rem];
  const unsigned short h = f2bf(f);
  const float r = f - bf2f(h);
  unsigned short* base = Whl + (size_t)mat * 2 * CC * CC;
  base[rem]           = h;
  base[CC*CC + rem]   = f2bf(r);
}

// ---------------------------------------------------------------------------
// Kernel 2: Q/K/U via bf16 split-precision MFMA, all three matrices per
// block (A-tile loaded+converted once; v HBM read 1x). R3 configuration:
// both hi/lo planes in LDS, [p][c][d] gather-friendly output layout.
// ---------------------------------------------------------------------------
__global__ __launch_bounds__(256, 2) void vn_gemm_mfma(
    const float* __restrict__ v, const unsigned short* __restrict__ Whl,
    float* __restrict__ Q, float* __restrict__ Kt, float* __restrict__ U)
{
  __shared__ short Wh[CC][WPAD];
  __shared__ short Wl[CC][WPAD];

  const int tid  = threadIdx.x;
  const int lane = tid & 63;
  const int wave = tid >> 6;
  const int quad = lane >> 4;
  const int l15  = lane & 15;

  const int m = blockIdx.x*64 + wave*16 + l15;
  const int p = m / 3, d = m - 3*p;
  const float* vb = v + (size_t)p * (CC*3) + d;
  float areg[32];
  #pragma unroll
  for (int kc = 0; kc < 4; ++kc)
    #pragma unroll
    for (int j = 0; j < 8; ++j)
      areg[kc*8+j] = vb[(kc*32 + quad*8 + j)*3];

  short8 ah[4], al[4];
  #pragma unroll
  for (int kc = 0; kc < 4; ++kc)
    #pragma unroll
    for (int j = 0; j < 8; ++j) {
      const float f = areg[kc*8+j];
      unsigned short h = f2bf(f);
      float r = f - bf2f(h);
      ah[kc][j] = (short)h;
      al[kc][j] = (short)f2bf(r);
    }

  const int r0s = blockIdx.x*64 + wave*16 + quad*4;
  int pbase[4];
  #pragma unroll
  for (int reg = 0; reg < 4; ++reg) {
    const int r = r0s + reg;
    const int pp = r / 3;
    pbase[reg] = pp * (CC*3) + (r - 3*pp);
  }
  const int l153 = l15 * 3;

  for (int mat = 0; mat < 3; ++mat) {
    float* __restrict__ Out = (mat == 0) ? Q : ((mat == 1) ? Kt : U);
    const unsigned short* Wg = Whl + (size_t)mat * 2 * CC * CC;

    #pragma unroll
    for (int it = 0; it < 8; ++it) {
      const int i = it*256 + tid;          // 2048 short8 chunks per plane
      const int o = i >> 4, c8 = (i & 15) * 8;
      *(short8*)&Wh[o][c8] = *(const short8*)&Wg[o*CC + c8];
      *(short8*)&Wl[o][c8] = *(const short8*)&Wg[CC*CC + o*CC + c8];
    }
    __syncthreads();

    floatx4 acc[8];
    #pragma unroll
    for (int ct = 0; ct < 8; ++ct) acc[ct] = (floatx4){0.f, 0.f, 0.f, 0.f};

    #pragma unroll
    for (int kc = 0; kc < 4; ++kc) {
      #pragma unroll
      for (int ct = 0; ct < 8; ++ct) {
        const int o = ct*16 + l15;
        const short8 bh = *(const short8*)&Wh[o][kc*32 + quad*8];
        const short8 bl = *(const short8*)&Wl[o][kc*32 + quad*8];
        acc[ct] = __builtin_amdgcn_mfma_f32_16x16x32_bf16(ah[kc], bh, acc[ct], 0, 0, 0);
        acc[ct] = __builtin_amdgcn_mfma_f32_16x16x32_bf16(al[kc], bh, acc[ct], 0, 0, 0);
        acc[ct] = __builtin_amdgcn_mfma_f32_16x16x32_bf16(ah[kc], bl, acc[ct], 0, 0, 0);
      }
    }
    __syncthreads();   // all waves' ds_reads done before next stage overwrites

    #pragma unroll
    for (int ct = 0; ct < 8; ++ct) {
      const int o3 = ct*48 + l153;
      #pragma unroll
      for (int reg = 0; reg < 4; ++reg)
        Out[pbase[reg] + o3] = acc[ct][reg];
    }
  }
}

// ---------------------------------------------------------------------------
// Kernel 3a: attention LOGITS pass — wave-per-point, zero barriers. R3 form
// (measured 65.2 µs): inline kn (the kn-table hoist cost more in its own
// launch than it saved here — reverted). K gathers L2-resident per XCD.
// ---------------------------------------------------------------------------
__global__ __launch_bounds__(256) void attn_logits_kernel(
    const float* __restrict__ x, const int* __restrict__ idx,
    const float* __restrict__ Q, const float* __restrict__ Kt,
    const float* __restrict__ W1, const float* __restrict__ b1,
    const float* __restrict__ W2, const float* __restrict__ b2,
    const float* __restrict__ W3, const float* __restrict__ b3,
    float* __restrict__ warr)
{
  const int lane = threadIdx.x & 63;
  const int wv   = threadIdx.x >> 6;
  // XCD swizzle: batch = blockIdx%8 (all 4 waves of a block share a batch)
  const int bn = ((blockIdx.x & 7) << 11) | (((blockIdx.x >> 3) << 2) | wv);
  const int b = bn >> 11;

  const float* Qp = Q + (size_t)bn * (CC*3) + lane*6;
  const floatx4u q0 = *(const floatx4u*)Qp;
  const float2 q1 = *(const float2*)(Qp+4);
  const float2 qa = make_float2(q0.x, q0.y);
  const float2 qb = make_float2(q0.z, q0.w);
  const float2 qc = make_float2(q1.x, q1.y);

  const int* ip = idx + (size_t)bn * KNB;
  int j[KNB];
  #pragma unroll
  for (int t = 0; t < KNB; ++t) j[t] = ip[t];

  // per-lane neighbor (kk = lane&15); issue dist gather EARLY
  const int kk = lane & 15;
  int jsel = j[0];
  #pragma unroll
  for (int t = 1; t < KNB; ++t) jsel = (kk == t) ? j[t] : jsel;

  const float xi0 = x[(size_t)bn*3+0], xi1 = x[(size_t)bn*3+1], xi2 = x[(size_t)bn*3+2];
  const float* xj = x + (size_t)(b*NN + jsel)*3;
  const float xj0 = xj[0], xj1 = xj[1], xj2 = xj[2];

  // K gather + dot partials + kn partials (inline, bitwise round-1 math)
  float dpart[KNB], knp[KNB];
  #pragma unroll
  for (int t = 0; t < KNB; ++t) {
    const float* Kp = Kt + (size_t)(b*NN + j[t]) * (CC*3) + lane*6;
    const floatx4u kv = *(const floatx4u*)Kp;
    const float2 kw = *(const float2*)(Kp+4);
    dpart[t] = qa.x*kv.x + qa.y*kv.y + qb.x*kv.z + qb.y*kv.w + qc.x*kw.x + qc.y*kw.y;
    knp[t] = fsqrt(kv.x*kv.x + kv.y*kv.y + kv.z*kv.z) + fsqrt(kv.w*kv.w + kw.x*kw.x + kw.y*kw.y);
  }
  float qnp = fsqrt(qa.x*qa.x + qa.y*qa.y + qb.x*qb.x) + fsqrt(qb.y*qb.y + qc.x*qc.x + qc.y*qc.y);

  // qn: full 64-lane butterfly (needed on every lane)
  #pragma unroll
  for (int off = 1; off < 64; off <<= 1) qnp += __shfl_xor(qnp, off, 64);
  const float s0 = qnp * (1.0f/128.0f);

  // dual-payload reduce-scatter: halve payloads at xor 1/2/4/8 against the
  // lane bit; each lane lands its kk's sums; xor 16/32 complete 64 lanes.
  float d8[8], k8[8];
  {
    const bool hb = (lane & 1) != 0;
    #pragma unroll
    for (int t = 0; t < 8; ++t) {
      const float dk = hb ? dpart[2*t+1] : dpart[2*t];
      const float dsn = hb ? dpart[2*t]  : dpart[2*t+1];
      const float kv = hb ? knp[2*t+1]   : knp[2*t];
      const float ksn = hb ? knp[2*t]    : knp[2*t+1];
      d8[t] = dk + __shfl_xor(dsn, 1, 64);
      k8[t] = kv + __shfl_xor(ksn, 1, 64);
    }
  }
  float d4[4], k4[4];
  {
    const bool hb = (lane & 2) != 0;
    #pragma unroll
    for (int t = 0; t < 4; ++t) {
      const float dk = hb ? d8[2*t+1] : d8[2*t];
      const float dsn = hb ? d8[2*t]  : d8[2*t+1];
      const float kv = hb ? k8[2*t+1] : k8[2*t];
      const float ksn = hb ? k8[2*t]  : k8[2*t+1];
      d4[t] = dk + __shfl_xor(dsn, 2, 64);
      k4[t] = kv + __shfl_xor(ksn, 2, 64);
    }
  }
  float d2a, d2b, k2a, k2b;
  {
    const bool hb = (lane & 4) != 0;
    const float dk0 = hb ? d4[1] : d4[0];
    const float dsn0 = hb ? d4[0] : d4[1];
    const float dk1 = hb ? d4[3] : d4[2];
    const float dsn1 = hb ? d4[2] : d4[3];
    d2a = dk0 + __shfl_xor(dsn0, 4, 64);
    d2b = dk1 + __shfl_xor(dsn1, 4, 64);
    const float kk0 = hb ? k4[1] : k4[0];
    const float ksn0 = hb ? k4[0] : k4[1];
    const float kk1 = hb ? k4[3] : k4[2];
    const float ksn1 = hb ? k4[2] : k4[3];
    k2a = kk0 + __shfl_xor(ksn0, 4, 64);
    k2b = kk1 + __shfl_xor(ksn1, 4, 64);
  }
  float dsel, knsel;
  {
    const bool hb = (lane & 8) != 0;
    const float dk = hb ? d2b : d2a;
    const float dsn = hb ? d2a : d2b;
    dsel = dk + __shfl_xor(dsn, 8, 64);
    const float kv = hb ? k2b : k2a;
    const float ksn = hb ? k2a : k2b;
    knsel = kv + __shfl_xor(ksn, 8, 64);
  }
  dsel  += __shfl_xor(dsel, 16, 64);
  dsel  += __shfl_xor(dsel, 32, 64);
  knsel += __shfl_xor(knsel, 16, 64);
  knsel += __shfl_xor(knsel, 32, 64);

  // dist feature
  const float dx = xi0 - xj0, dy = xi1 - xj1, dz = xi2 - xj2;
  const float s3 = fsqrt(dx*dx + dy*dy + dz*dz);
  const float s1 = knsel * (1.0f/128.0f);
  const float s2 = dsel * (1.0f/128.0f);

  // ---- edge MLP, h-split across the 4 redundant lane groups (g = lane>>4).
  const int g = lane >> 4;
  const int o0 = g*8, o1 = (g^1)*8, o2 = (g^2)*8, o3 = (g^3)*8;

  float h1o[8];
  {
    const float4 b1a = *(const float4*)(b1 + o0);
    const float4 b1b = *(const float4*)(b1 + o0 + 4);
    const float bb1[8] = {b1a.x,b1a.y,b1a.z,b1a.w,b1b.x,b1b.y,b1b.z,b1b.w};
    #pragma unroll
    for (int jj = 0; jj < 8; ++jj) {
      const float4 w = *(const float4*)(W1 + (o0 + jj)*4);
      float u = bb1[jj];
      u = fmaf(w.x, s0, u); u = fmaf(w.y, s1, u);
      u = fmaf(w.z, s2, u); u = fmaf(w.w, s3, u);
      h1o[jj] = silu_f(u);
    }
  }
  float hx16[8], hx32[8], hx48[8];
  #pragma unroll
  for (int jj = 0; jj < 8; ++jj) hx16[jj] = __shfl_xor(h1o[jj], 16, 64);
  #pragma unroll
  for (int jj = 0; jj < 8; ++jj) hx32[jj] = __shfl_xor(h1o[jj], 32, 64);
  #pragma unroll
  for (int jj = 0; jj < 8; ++jj) hx48[jj] = __shfl_xor(hx16[jj], 32, 64);

  float logit;
  {
    const float4 b2a = *(const float4*)(b2 + o0);
    const float4 b2b = *(const float4*)(b2 + o0 + 4);
    const float bb2[8] = {b2a.x,b2a.y,b2a.z,b2a.w,b2b.x,b2b.y,b2b.z,b2b.w};
    const float4 w3a = *(const float4*)(W3 + o0);
    const float4 w3b = *(const float4*)(W3 + o0 + 4);
    const float ww3[8] = {w3a.x,w3a.y,w3a.z,w3a.w,w3b.x,w3b.y,w3b.z,w3b.w};
    float lp = 0.f;
    #pragma unroll
    for (int hh = 0; hh < 8; ++hh) {
      const float* wr = W2 + (o0 + hh)*32;    // row h = g*8+hh
      float a = bb2[hh];
      a += dot8(wr + o0, h1o);
      a += dot8(wr + o1, hx16);
      a += dot8(wr + o2, hx32);
      a += dot8(wr + o3, hx48);
      lp = fmaf(ww3[hh], silu_f(a), lp);
    }
    lp += __shfl_xor(lp, 16, 64);
    lp += __shfl_xor(lp, 32, 64);
    logit = lp + b3[0];
  }
  logit = fminf(fmaxf(logit, -10.0f), 10.0f);

  // softmax over the 16-lane group
  float mx = logit;
  #pragma unroll
  for (int off = 8; off > 0; off >>= 1) mx = fmaxf(mx, __shfl_xor(mx, off, 16));
  const float e = __builtin_amdgcn_exp2f(1.442695040888963f * (logit - mx));
  float ssum = e;
  #pragma unroll
  for (int off = 8; off > 0; off >>= 1) ssum += __shfl_xor(ssum, off, 16);
  const float w = e * frcp(ssum);

  // groups hold identical w for kk=lane&15; lanes 0..15 write the 16 weights
  if (lane < KNB) warr[(size_t)bn * KNB + lane] = w;
}

// ---------------------------------------------------------------------------
// Kernel 3b: attention MESSAGE pass — wave-per-point. U gathers L2-resident
// (3 MB/batch per XCD); message + residual + VN layer norm + clamp + store.
// ---------------------------------------------------------------------------
__global__ __launch_bounds__(256) void attn_msg_kernel(
    const int* __restrict__ idx, const float* __restrict__ Q,
    const float* __restrict__ U, const float* __restrict__ warr,
    const float* __restrict__ gam, const float* __restrict__ bet,
    float* __restrict__ out)
{
  const int lane = threadIdx.x & 63;
  const int wv   = threadIdx.x >> 6;
  const int bn = ((blockIdx.x & 7) << 11) | (((blockIdx.x >> 3) << 2) | wv);
  const int b = bn >> 11;

  // idx first -> U gather addresses resolve ASAP (everything else independent)
  const int* ip = idx + (size_t)bn * KNB;
  int j[KNB];
  #pragma unroll
  for (int t = 0; t < KNB; ++t) j[t] = ip[t];

  const float* Qp = Q + (size_t)bn * (CC*3) + lane*6;
  const floatx4u q0 = *(const floatx4u*)Qp;
  const float2 q1 = *(const float2*)(Qp+4);

  const float* wp = warr + (size_t)bn * KNB;
  float wk[KNB];
  #pragma unroll
  for (int t = 0; t < KNB; ++t) wk[t] = wp[t];

  // message: gather U rows, accumulate in t order (bitwise same as before)
  float m0=0.f,m1=0.f,m2=0.f,m3=0.f,m4=0.f,m5=0.f;
  #pragma unroll
  for (int t = 0; t < KNB; ++t) {
    const float* Up = U + (size_t)(b*NN + j[t]) * (CC*3) + lane*6;
    const floatx4u uv = *(const floatx4u*)Up;
    const float2 uw = *(const float2*)(Up+4);
    const float ww = wk[t];
    m0 = fmaf(ww, uv.x, m0); m1 = fmaf(ww, uv.y, m1); m2 = fmaf(ww, uv.z, m2);
    m3 = fmaf(ww, uv.w, m3); m4 = fmaf(ww, uw.x, m4); m5 = fmaf(ww, uw.y, m5);
  }
  const float oa0 = q0.x + 0.5f*m0, oa1 = q0.y + 0.5f*m1, oa2 = q0.z + 0.5f*m2;
  const float ob0 = q0.w + 0.5f*m3, ob1 = q1.x + 0.5f*m4, ob2 = q1.y + 0.5f*m5;

  // VN layer norm (two channels per lane)
  const float na = fmaxf(fsqrt(oa0*oa0 + oa1*oa1 + oa2*oa2), 1e-6f);
  const float nb = fmaxf(fsqrt(ob0*ob0 + ob1*ob1 + ob2*ob2), 1e-6f);
  float s = na + nb;
  #pragma unroll
  for (int off = 1; off < 64; off <<= 1) s += __shfl_xor(s, off, 64);
  const float mean = s * (1.0f/128.0f);
  const float dva = na - mean, dvb = nb - mean;
  float s2v = dva*dva + dvb*dvb;
  #pragma unroll
  for (int off = 1; off < 64; off <<= 1) s2v += __shfl_xor(s2v, off, 64);
  const float stdv = fmaxf(fsqrt(s2v * (1.0f/127.0f)), 1e-6f);
  const float rstd = frcp(stdv);

  const float2 gm = *(const float2*)(gam + lane*2);
  const float2 bt = *(const float2*)(bet + lane*2);
  const float nsa = (na - mean) * rstd * gm.x + bt.x;
  const float nsb = (nb - mean) * rstd * gm.y + bt.y;
  const float sca = fmaxf(nsa, 1e-6f) * frcp(na);
  const float scb = fmaxf(nsb, 1e-6f) * frcp(nb);
  float fa0 = oa0*sca, fa1 = oa1*sca, fa2 = oa2*sca;
  float fb0 = ob0*scb, fb1 = ob1*scb, fb2 = ob2*scb;
  const float n2a = fmaxf(fsqrt(fa0*fa0 + fa1*fa1 + fa2*fa2), 1e-6f);
  const float n2b = fmaxf(fsqrt(fb0*fb0 + fb1*fb1 + fb2*fb2), 1e-6f);
  const float c2a = fminf(50.0f * frcp(n2a), 1.0f);
  const float c2b = fminf(50.0f * frcp(n2b), 1.0f);

  float* op = out + (size_t)bn * (CC*3) + lane*6;
  floatx4u o4; o4.x = fa0*c2a; o4.y = fa1*c2a; o4.z = fa2*c2a; o4.w = fb0*c2b;
  *(floatx4u*)op = o4;
  *(float2*)(op+4) = make_float2(fb1*c2b, fb2*c2b);
}

// ---------------------------------------------------------------------------
extern "C" void kernel_launch(void* const* d_in, const int* in_sizes, int n_in,
                              void* d_out, int out_size, void* d_ws, size_t ws_size,
                              hipStream_t stream) {
  (void)in_sizes; (void)n_in; (void)out_size; (void)ws_size;
  const float* x   = (const float*)d_in[0];
  const float* v   = (const float*)d_in[1];
  const float* Wq  = (const float*)d_in[2];
  const float* Wk  = (const float*)d_in[3];
  const float* Wu  = (const float*)d_in[4];
  const float* W1  = (const float*)d_in[5];
  const float* b1  = (const float*)d_in[6];
  const float* W2  = (const float*)d_in[7];
  const float* b2  = (const float*)d_in[8];
  const float* W3  = (const float*)d_in[9];
  const float* b3  = (const float*)d_in[10];
  const float* gam = (const float*)d_in[11];
  const float* bet = (const float*)d_in[12];
  float* out = (float*)d_out;

  char* ws = (char*)d_ws;
  int*   idx = (int*)ws;                                  // BN*16 ints (1 MB)
  float* Q   = (float*)(ws + (size_t)BN * KNB * 4);       // BN*384 floats
  float* Kt  = Q  + (size_t)BN * CC * 3;
  float* U   = Kt + (size_t)BN * CC * 3;
  unsigned short* Whl = (unsigned short*)(U + (size_t)BN * CC * 3);  // 3*2*128*128 bf16
  float* warr = (float*)((char*)Whl + (size_t)3 * 2 * CC * CC * 2);  // BN*16 floats (1 MB)
  double* sqd = (double*)(warr + (size_t)BN * KNB);       // BN doubles (128 KB)
  float4* x4  = (float4*)(sqd + (size_t)BN);              // BN float4 (256 KB)

  sq_kernel<<<BN/256, 256, 0, stream>>>(x, sqd, x4);
  knn_kernel<<<BN/4, 256, 0, stream>>>(x4, sqd, idx);
  wconv_kernel<<<192, 256, 0, stream>>>(Wq, Wk, Wu, Whl);
  vn_gemm_mfma<<<(BN*3)/64, 256, 0, stream>>>(v, Whl, Q, Kt, U);
  attn_logits_kernel<<<BN/4, 256, 0, stream>>>(x, idx, Q, Kt,
                                               W1, b1, W2, b2, W3, b3, warr);
  attn_msg_kernel<<<BN/4, 256, 0, stream>>>(idx, Q, U, warr, gam, bet, out);
}

// Round 7
// 252.441 us; speedup vs baseline: 1.1202x; 1.1000x over previous
//
#include <hip/hip_runtime.h>
#include <math.h>

#define BB 8
#define NN 2048
#define CC 128
#define KNB 16
#define BN (BB*NN)
#define WPAD 136       // LDS row pad for W (16B-aligned rows, 2-way banks only)

#define EMPTYK 0xFFFFFFFFFFFFFFFFULL

typedef __attribute__((ext_vector_type(8))) short short8;
typedef __attribute__((ext_vector_type(4))) float floatx4;
typedef __attribute__((ext_vector_type(4), aligned(4))) float floatx4u;  // 4B-aligned float4

// fast silu: x / (1 + e^-x) via v_exp_f32 + v_rcp_f32 (~1 ulp, plenty here)
__device__ __forceinline__ float silu_f(float x) {
  const float e = __builtin_amdgcn_exp2f(-1.442695040888963f * x);
  return x * __builtin_amdgcn_rcpf(1.0f + e);
}
__device__ __forceinline__ float fsqrt(float x) { return __builtin_amdgcn_sqrtf(x); }
__device__ __forceinline__ float frcp(float x)  { return __builtin_amdgcn_rcpf(x); }

__device__ __forceinline__ unsigned long long umin64(unsigned long long a, unsigned long long b) {
  return (b < a) ? b : a;
}

__device__ __forceinline__ unsigned short f2bf(float f) {   // RNE
  unsigned u = __float_as_uint(f);
  unsigned r = u + 0x7FFFu + ((u >> 16) & 1u);
  return (unsigned short)(r >> 16);
}
__device__ __forceinline__ float bf2f(unsigned short s) {
  return __uint_as_float(((unsigned)s) << 16);
}

// 8-wide dot: 2 float4 loads + 8 FMA (works for global or LDS pointers)
__device__ __forceinline__ float dot8(const float* __restrict__ w, const float* __restrict__ h) {
  const float4 a = *(const float4*)w;
  const float4 b = *(const float4*)(w + 4);
  float s = a.x*h[0];
  s = fmaf(a.y, h[1], s); s = fmaf(a.z, h[2], s); s = fmaf(a.w, h[3], s);
  s = fmaf(b.x, h[4], s); s = fmaf(b.y, h[5], s); s = fmaf(b.z, h[6], s);
  s = fmaf(b.w, h[7], s);
  return s;
}

// ---------------------------------------------------------------------------
// Kernel 0: per-point f64 squared-norm + packed float4 (x,y,z,0) table.
// ---------------------------------------------------------------------------
__global__ __launch_bounds__(256) void sq_kernel(const float* __restrict__ x,
                                                 double* __restrict__ sqd,
                                                 float4* __restrict__ x4) {
  const int i = blockIdx.x*256 + threadIdx.x;      // 0..BN-1
  const float f0 = x[i*3+0], f1 = x[i*3+1], f2 = x[i*3+2];
  const double a0 = (double)f0, a1 = (double)f1, a2 = (double)f2;
  sqd[i] = a0*a0 + a1*a1 + a2*a2;
  x4[i] = make_float4(f0, f1, f2, 0.0f);
}

// ---------------------------------------------------------------------------
// Kernel 1: kNN — one WAVE per query, 4 waves/block, no LDS, no barriers.
// NEW: candidate keys are NOT stored (k[32] cost 64 VGPRs -> spill/low
// occupancy, r5/r6). Refill (rare: P(lane owns >=4 of top-16) ~ 0.7%)
// RECOMPUTES the lane's keys with the bitwise-identical f64 expression
// from the L1-hot x4/sqd tables. Register footprint ~60 VGPR -> ~8
// waves/SIMD hides the selection butterfly's serial shuffle latency.
// Selection: u32 high-word butterfly + ballot/readlane, exact low-word
// fallback on ties (ordering identical to the u64 butterfly).
// ---------------------------------------------------------------------------
__global__ __launch_bounds__(256) void knn_kernel(const float4* __restrict__ x4,
                                                  const double* __restrict__ sqd,
                                                  int* __restrict__ idx) {
  const int lane = threadIdx.x & 63;
  const int wave = threadIdx.x >> 6;
  const int bn = blockIdx.x * 4 + wave;
  const int b = bn >> 11;
  const int n = bn & (NN - 1);

  const float4* xb4 = x4 + (size_t)b * NN;
  const double* sqb = sqd + (size_t)b * NN;
  const float4 xq = xb4[n];
  const double xn0 = (double)xq.x, xn1 = (double)xq.y, xn2 = (double)xq.z;
  const double sqn = sqb[n];

  unsigned long long t0 = EMPTYK, t1 = EMPTYK, t2 = EMPTYK, t3 = EMPTYK;

  #pragma unroll 8
  for (int i = 0; i < 32; ++i) {
    const int m = i*64 + lane;
    const float4 xm = xb4[m];
    const double a0 = (double)xm.x, a1 = (double)xm.y, a2 = (double)xm.z;
    const double sqm = sqb[m];
    const double dot = xn0*a0 + xn1*a1 + xn2*a2;
    const double d = sqn + sqm - 2.0*dot;
    unsigned long long kk =
        ((unsigned long long)__double_as_longlong(d) & ~2047ULL) | (unsigned long long)m;
    if (m == n) kk = 0x8000000000000000ULL | (unsigned long long)m;
    const bool l3 = kk < t3, l2 = kk < t2, l1 = kk < t1, l0 = kk < t0;
    t3 = l3 ? (l2 ? t2 : kk) : t3;
    t2 = l2 ? (l1 ? t1 : kk) : t2;
    t1 = l1 ? (l0 ? t0 : kk) : t1;
    t0 = l0 ? kk : t0;
  }

  int* op = idx + (size_t)bn * KNB;
  for (int t = 0; t < KNB; ++t) {
    const unsigned h0 = (unsigned)(t0 >> 32);
    const unsigned l0w = (unsigned)t0;
    unsigned hm = h0;
    #pragma unroll
    for (int off = 32; off > 0; off >>= 1) {
      const unsigned o = (unsigned)__shfl_xor((int)hm, off, 64);
      hm = (o < hm) ? o : hm;
    }
    const bool tied = (h0 == hm);
    const unsigned long long bal = __ballot(tied);
    unsigned lm;
    if (__builtin_popcountll(bal) == 1) {
      const int owner = __builtin_ctzll(bal);
      lm = (unsigned)__shfl((int)l0w, owner, 64);
    } else {
      lm = tied ? l0w : 0xFFFFFFFFu;
      #pragma unroll
      for (int off = 32; off > 0; off >>= 1) {
        const unsigned o = (unsigned)__shfl_xor((int)lm, off, 64);
        lm = (o < lm) ? o : lm;
      }
    }
    const unsigned long long g = ((unsigned long long)hm << 32) | (unsigned long long)lm;

    if (lane == 0) op[t] = (int)(lm & 2047u);

    const bool own = tied && (l0w == lm);
    t0 = own ? t1 : t0;
    t1 = own ? t2 : t1;
    t2 = own ? t3 : t2;
    t3 = own ? EMPTYK : t3;

    const bool need = (t0 == EMPTYK);
    if (__any(need)) {
      // cold path: recompute this lane's keys (bitwise-identical expression)
      unsigned long long nm = EMPTYK;
      #pragma unroll 1
      for (int i = 0; i < 32; ++i) {
        const int m = i*64 + lane;
        const float4 xm = xb4[m];
        const double a0 = (double)xm.x, a1 = (double)xm.y, a2 = (double)xm.z;
        const double sqm = sqb[m];
        const double dot = xn0*a0 + xn1*a1 + xn2*a2;
        const double d = sqn + sqm - 2.0*dot;
        unsigned long long kk =
            ((unsigned long long)__double_as_longlong(d) & ~2047ULL) | (unsigned long long)m;
        if (m == n) kk = 0x8000000000000000ULL | (unsigned long long)m;
        const unsigned long long c = (kk > g) ? kk : EMPTYK;
        nm = umin64(nm, c);
      }
      t0 = need ? nm : t0;
    }
  }
}

// ---------------------------------------------------------------------------
// Kernel 1b: W pre-conversion — f32 -> bf16 hi/lo planes, once per matrix.
// ---------------------------------------------------------------------------
__global__ __launch_bounds__(256) void wconv_kernel(
    const float* __restrict__ Wq, const float* __restrict__ Wk, const float* __restrict__ Wu,
    unsigned short* __restrict__ Whl)
{
  const int i = blockIdx.x*256 + threadIdx.x;      // 0..49151
  const int mat = i >> 14, rem = i & 16383;
  const float* W = (mat == 0) ? Wq : ((mat == 1) ? Wk : Wu);
  const float f = W[rem];
  const unsigned short h = f2bf(f);
  const float r = f - bf2f(h);
  unsigned short* base = Whl + (size_t)mat * 2 * CC * CC;
  base[rem]           = h;
  base[CC*CC + rem]   = f2bf(r);
}

// ---------------------------------------------------------------------------
// Kernel 2: Q/K/U via bf16 split-precision MFMA, all three matrices per
// block (A-tile loaded+converted once; v HBM read 1x). Unchanged from r6.
// ---------------------------------------------------------------------------
__global__ __launch_bounds__(256, 2) void vn_gemm_mfma(
    const float* __restrict__ v, const unsigned short* __restrict__ Whl,
    float* __restrict__ Q, float* __restrict__ Kt, float* __restrict__ U)
{
  __shared__ short Wh[CC][WPAD];
  __shared__ short Wl[CC][WPAD];

  const int tid  = threadIdx.x;
  const int lane = tid & 63;
  const int wave = tid >> 6;
  const int quad = lane >> 4;
  const int l15  = lane & 15;

  const int m = blockIdx.x*64 + wave*16 + l15;
  const int p = m / 3, d = m - 3*p;
  const float* vb = v + (size_t)p * (CC*3) + d;
  float areg[32];
  #pragma unroll
  for (int kc = 0; kc < 4; ++kc)
    #pragma unroll
    for (int j = 0; j < 8; ++j)
      areg[kc*8+j] = vb[(kc*32 + quad*8 + j)*3];

  short8 ah[4], al[4];
  #pragma unroll
  for (int kc = 0; kc < 4; ++kc)
    #pragma unroll
    for (int j = 0; j < 8; ++j) {
      const float f = areg[kc*8+j];
      unsigned short h = f2bf(f);
      float r = f - bf2f(h);
      ah[kc][j] = (short)h;
      al[kc][j] = (short)f2bf(r);
    }

  const int r0s = blockIdx.x*64 + wave*16 + quad*4;
  int pbase[4];
  #pragma unroll
  for (int reg = 0; reg < 4; ++reg) {
    const int r = r0s + reg;
    const int pp = r / 3;
    pbase[reg] = pp * (CC*3) + (r - 3*pp);
  }
  const int l153 = l15 * 3;

  for (int mat = 0; mat < 3; ++mat) {
    float* __restrict__ Out = (mat == 0) ? Q : ((mat == 1) ? Kt : U);
    const unsigned short* Wg = Whl + (size_t)mat * 2 * CC * CC;

    #pragma unroll
    for (int it = 0; it < 8; ++it) {
      const int i = it*256 + tid;          // 2048 short8 chunks per plane
      const int o = i >> 4, c8 = (i & 15) * 8;
      *(short8*)&Wh[o][c8] = *(const short8*)&Wg[o*CC + c8];
      *(short8*)&Wl[o][c8] = *(const short8*)&Wg[CC*CC + o*CC + c8];
    }
    __syncthreads();

    floatx4 acc[8];
    #pragma unroll
    for (int ct = 0; ct < 8; ++ct) acc[ct] = (floatx4){0.f, 0.f, 0.f, 0.f};

    #pragma unroll
    for (int kc = 0; kc < 4; ++kc) {
      #pragma unroll
      for (int ct = 0; ct < 8; ++ct) {
        const int o = ct*16 + l15;
        const short8 bh = *(const short8*)&Wh[o][kc*32 + quad*8];
        const short8 bl = *(const short8*)&Wl[o][kc*32 + quad*8];
        acc[ct] = __builtin_amdgcn_mfma_f32_16x16x32_bf16(ah[kc], bh, acc[ct], 0, 0, 0);
        acc[ct] = __builtin_amdgcn_mfma_f32_16x16x32_bf16(al[kc], bh, acc[ct], 0, 0, 0);
        acc[ct] = __builtin_amdgcn_mfma_f32_16x16x32_bf16(ah[kc], bl, acc[ct], 0, 0, 0);
      }
    }
    __syncthreads();   // all waves' ds_reads done before next stage overwrites

    #pragma unroll
    for (int ct = 0; ct < 8; ++ct) {
      const int o3 = ct*48 + l153;
      #pragma unroll
      for (int reg = 0; reg < 4; ++reg)
        Out[pbase[reg] + o3] = acc[ct][reg];
    }
  }
}

// ---------------------------------------------------------------------------
// Kernel 3a: attention LOGITS pass — wave-per-point. NEW: MLP weights
// (W1/b1/W2/b2/W3/b3, 4.7 KB) staged in LDS once per block (one barrier);
// the 32 dot8 calls per lane (64 float4 VMEM loads, half the kernel's VMEM
// issue) become broadcast ds_read_b128 on the otherwise-idle DS pipe.
// All arithmetic bitwise-identical to r6.
// ---------------------------------------------------------------------------
__global__ __launch_bounds__(256) void attn_logits_kernel(
    const float* __restrict__ x, const int* __restrict__ idx,
    const float* __restrict__ Q, const float* __restrict__ Kt,
    const float* __restrict__ W1, const float* __restrict__ b1,
    const float* __restrict__ W2, const float* __restrict__ b2,
    const float* __restrict__ W3, const float* __restrict__ b3,
    float* __restrict__ warr)
{
  __shared__ __align__(16) float W2s[32][32];
  __shared__ __align__(16) float W1s[32][4];
  __shared__ __align__(16) float b1s[32];
  __shared__ __align__(16) float b2s[32];
  __shared__ __align__(16) float W3s[32];
  __shared__ float b3s;

  const int tid  = threadIdx.x;
  const int lane = tid & 63;
  const int wv   = tid >> 6;
  // XCD swizzle: batch = blockIdx%8 (all 4 waves of a block share a batch)
  const int bn = ((blockIdx.x & 7) << 11) | (((blockIdx.x >> 3) << 2) | wv);
  const int b = bn >> 11;

  // issue per-point loads first so they are in flight across the staging
  const float* Qp = Q + (size_t)bn * (CC*3) + lane*6;
  const floatx4u q0 = *(const floatx4u*)Qp;
  const float2 q1 = *(const float2*)(Qp+4);

  const int* ip = idx + (size_t)bn * KNB;
  int j[KNB];
  #pragma unroll
  for (int t = 0; t < KNB; ++t) j[t] = ip[t];

  // stage MLP weights to LDS (one-time, ~4.7 KB)
  #pragma unroll
  for (int it = 0; it < 4; ++it)
    ((float*)W2s)[it*256 + tid] = W2[it*256 + tid];
  if (tid < 128) ((float*)W1s)[tid] = W1[tid];
  if (tid < 32) { b1s[tid] = b1[tid]; b2s[tid] = b2[tid]; W3s[tid] = W3[tid]; }
  if (tid == 0) b3s = b3[0];
  __syncthreads();

  const float2 qa = make_float2(q0.x, q0.y);
  const float2 qb = make_float2(q0.z, q0.w);
  const float2 qc = make_float2(q1.x, q1.y);

  // per-lane neighbor (kk = lane&15); issue dist gather EARLY
  const int kk = lane & 15;
  int jsel = j[0];
  #pragma unroll
  for (int t = 1; t < KNB; ++t) jsel = (kk == t) ? j[t] : jsel;

  const float xi0 = x[(size_t)bn*3+0], xi1 = x[(size_t)bn*3+1], xi2 = x[(size_t)bn*3+2];
  const float* xj = x + (size_t)(b*NN + jsel)*3;
  const float xj0 = xj[0], xj1 = xj[1], xj2 = xj[2];

  // K gather + dot partials + kn partials
  float dpart[KNB], knp[KNB];
  #pragma unroll
  for (int t = 0; t < KNB; ++t) {
    const float* Kp = Kt + (size_t)(b*NN + j[t]) * (CC*3) + lane*6;
    const floatx4u kv = *(const floatx4u*)Kp;
    const float2 kw = *(const float2*)(Kp+4);
    dpart[t] = qa.x*kv.x + qa.y*kv.y + qb.x*kv.z + qb.y*kv.w + qc.x*kw.x + qc.y*kw.y;
    knp[t] = fsqrt(kv.x*kv.x + kv.y*kv.y + kv.z*kv.z) + fsqrt(kv.w*kv.w + kw.x*kw.x + kw.y*kw.y);
  }
  float qnp = fsqrt(qa.x*qa.x + qa.y*qa.y + qb.x*qb.x) + fsqrt(qb.y*qb.y + qc.x*qc.x + qc.y*qc.y);

  // qn: full 64-lane butterfly (needed on every lane)
  #pragma unroll
  for (int off = 1; off < 64; off <<= 1) qnp += __shfl_xor(qnp, off, 64);
  const float s0 = qnp * (1.0f/128.0f);

  // dual-payload reduce-scatter: halve payloads at xor 1/2/4/8 against the
  // lane bit; each lane lands its kk's sums; xor 16/32 complete 64 lanes.
  float d8[8], k8[8];
  {
    const bool hb = (lane & 1) != 0;
    #pragma unroll
    for (int t = 0; t < 8; ++t) {
      const float dk = hb ? dpart[2*t+1] : dpart[2*t];
      const float dsn = hb ? dpart[2*t]  : dpart[2*t+1];
      const float kv = hb ? knp[2*t+1]   : knp[2*t];
      const float ksn = hb ? knp[2*t]    : knp[2*t+1];
      d8[t] = dk + __shfl_xor(dsn, 1, 64);
      k8[t] = kv + __shfl_xor(ksn, 1, 64);
    }
  }
  float d4[4], k4[4];
  {
    const bool hb = (lane & 2) != 0;
    #pragma unroll
    for (int t = 0; t < 4; ++t) {
      const float dk = hb ? d8[2*t+1] : d8[2*t];
      const float dsn = hb ? d8[2*t]  : d8[2*t+1];
      const float kv = hb ? k8[2*t+1] : k8[2*t];
      const float ksn = hb ? k8[2*t]  : k8[2*t+1];
      d4[t] = dk + __shfl_xor(dsn, 2, 64);
      k4[t] = kv + __shfl_xor(ksn, 2, 64);
    }
  }
  float d2a, d2b, k2a, k2b;
  {
    const bool hb = (lane & 4) != 0;
    const float dk0 = hb ? d4[1] : d4[0];
    const float dsn0 = hb ? d4[0] : d4[1];
    const float dk1 = hb ? d4[3] : d4[2];
    const float dsn1 = hb ? d4[2] : d4[3];
    d2a = dk0 + __shfl_xor(dsn0, 4, 64);
    d2b = dk1 + __shfl_xor(dsn1, 4, 64);
    const float kk0 = hb ? k4[1] : k4[0];
    const float ksn0 = hb ? k4[0] : k4[1];
    const float kk1 = hb ? k4[3] : k4[2];
    const float ksn1 = hb ? k4[2] : k4[3];
    k2a = kk0 + __shfl_xor(ksn0, 4, 64);
    k2b = kk1 + __shfl_xor(ksn1, 4, 64);
  }
  float dsel, knsel;
  {
    const bool hb = (lane & 8) != 0;
    const float dk = hb ? d2b : d2a;
    const float dsn = hb ? d2a : d2b;
    dsel = dk + __shfl_xor(dsn, 8, 64);
    const float kv = hb ? k2b : k2a;
    const float ksn = hb ? k2a : k2b;
    knsel = kv + __shfl_xor(ksn, 8, 64);
  }
  dsel  += __shfl_xor(dsel, 16, 64);
  dsel  += __shfl_xor(dsel, 32, 64);
  knsel += __shfl_xor(knsel, 16, 64);
  knsel += __shfl_xor(knsel, 32, 64);

  // dist feature
  const float dx = xi0 - xj0, dy = xi1 - xj1, dz = xi2 - xj2;
  const float s3 = fsqrt(dx*dx + dy*dy + dz*dz);
  const float s1 = knsel * (1.0f/128.0f);
  const float s2 = dsel * (1.0f/128.0f);

  // ---- edge MLP, h-split across the 4 redundant lane groups (g = lane>>4).
  const int g = lane >> 4;
  const int o0 = g*8, o1 = (g^1)*8, o2 = (g^2)*8, o3 = (g^3)*8;

  float h1o[8];
  {
    const float4 b1a = *(const float4*)&b1s[o0];
    const float4 b1b = *(const float4*)&b1s[o0 + 4];
    const float bb1[8] = {b1a.x,b1a.y,b1a.z,b1a.w,b1b.x,b1b.y,b1b.z,b1b.w};
    #pragma unroll
    for (int jj = 0; jj < 8; ++jj) {
      const float4 w = *(const float4*)&W1s[o0 + jj][0];
      float u = bb1[jj];
      u = fmaf(w.x, s0, u); u = fmaf(w.y, s1, u);
      u = fmaf(w.z, s2, u); u = fmaf(w.w, s3, u);
      h1o[jj] = silu_f(u);
    }
  }
  float hx16[8], hx32[8], hx48[8];
  #pragma unroll
  for (int jj = 0; jj < 8; ++jj) hx16[jj] = __shfl_xor(h1o[jj], 16, 64);
  #pragma unroll
  for (int jj = 0; jj < 8; ++jj) hx32[jj] = __shfl_xor(h1o[jj], 32, 64);
  #pragma unroll
  for (int jj = 0; jj < 8; ++jj) hx48[jj] = __shfl_xor(hx16[jj], 32, 64);

  float logit;
  {
    const float4 b2a = *(const float4*)&b2s[o0];
    const float4 b2b = *(const float4*)&b2s[o0 + 4];
    const float bb2[8] = {b2a.x,b2a.y,b2a.z,b2a.w,b2b.x,b2b.y,b2b.z,b2b.w};
    const float4 w3a = *(const float4*)&W3s[o0];
    const float4 w3b = *(const float4*)&W3s[o0 + 4];
    const float ww3[8] = {w3a.x,w3a.y,w3a.z,w3a.w,w3b.x,w3b.y,w3b.z,w3b.w};
    float lp = 0.f;
    #pragma unroll
    for (int hh = 0; hh < 8; ++hh) {
      const float* wr = &W2s[o0 + hh][0];    // row h = g*8+hh (LDS, broadcast)
      float a = bb2[hh];
      a += dot8(wr + o0, h1o);
      a += dot8(wr + o1, hx16);
      a += dot8(wr + o2, hx32);
      a += dot8(wr + o3, hx48);
      lp = fmaf(ww3[hh], silu_f(a), lp);
    }
    lp += __shfl_xor(lp, 16, 64);
    lp += __shfl_xor(lp, 32, 64);
    logit = lp + b3s;
  }
  logit = fminf(fmaxf(logit, -10.0f), 10.0f);

  // softmax over the 16-lane group
  float mx = logit;
  #pragma unroll
  for (int off = 8; off > 0; off >>= 1) mx = fmaxf(mx, __shfl_xor(mx, off, 16));
  const float e = __builtin_amdgcn_exp2f(1.442695040888963f * (logit - mx));
  float ssum = e;
  #pragma unroll
  for (int off = 8; off > 0; off >>= 1) ssum += __shfl_xor(ssum, off, 16);
  const float w = e * frcp(ssum);

  // groups hold identical w for kk=lane&15; lanes 0..15 write the 16 weights
  if (lane < KNB) warr[(size_t)bn * KNB + lane] = w;
}

// ---------------------------------------------------------------------------
// Kernel 3b: attention MESSAGE pass — wave-per-point. Unchanged from r6.
// ---------------------------------------------------------------------------
__global__ __launch_bounds__(256) void attn_msg_kernel(
    const int* __restrict__ idx, const float* __restrict__ Q,
    const float* __restrict__ U, const float* __restrict__ warr,
    const float* __restrict__ gam, const float* __restrict__ bet,
    float* __restrict__ out)
{
  const int lane = threadIdx.x & 63;
  const int wv   = threadIdx.x >> 6;
  const int bn = ((blockIdx.x & 7) << 11) | (((blockIdx.x >> 3) << 2) | wv);
  const int b = bn >> 11;

  // idx first -> U gather addresses resolve ASAP (everything else independent)
  const int* ip = idx + (size_t)bn * KNB;
  int j[KNB];
  #pragma unroll
  for (int t = 0; t < KNB; ++t) j[t] = ip[t];

  const float* Qp = Q + (size_t)bn * (CC*3) + lane*6;
  const floatx4u q0 = *(const floatx4u*)Qp;
  const float2 q1 = *(const float2*)(Qp+4);

  const float* wp = warr + (size_t)bn * KNB;
  float wk[KNB];
  #pragma unroll
  for (int t = 0; t < KNB; ++t) wk[t] = wp[t];

  // message: gather U rows, accumulate in t order (bitwise same as before)
  float m0=0.f,m1=0.f,m2=0.f,m3=0.f,m4=0.f,m5=0.f;
  #pragma unroll
  for (int t = 0; t < KNB; ++t) {
    const float* Up = U + (size_t)(b*NN + j[t]) * (CC*3) + lane*6;
    const floatx4u uv = *(const floatx4u*)Up;
    const float2 uw = *(const float2*)(Up+4);
    const float ww = wk[t];
    m0 = fmaf(ww, uv.x, m0); m1 = fmaf(ww, uv.y, m1); m2 = fmaf(ww, uv.z, m2);
    m3 = fmaf(ww, uv.w, m3); m4 = fmaf(ww, uw.x, m4); m5 = fmaf(ww, uw.y, m5);
  }
  const float oa0 = q0.x + 0.5f*m0, oa1 = q0.y + 0.5f*m1, oa2 = q0.z + 0.5f*m2;
  const float ob0 = q0.w + 0.5f*m3, ob1 = q1.x + 0.5f*m4, ob2 = q1.y + 0.5f*m5;

  // VN layer norm (two channels per lane)
  const float na = fmaxf(fsqrt(oa0*oa0 + oa1*oa1 + oa2*oa2), 1e-6f);
  const float nb = fmaxf(fsqrt(ob0*ob0 + ob1*ob1 + ob2*ob2), 1e-6f);
  float s = na + nb;
  #pragma unroll
  for (int off = 1; off < 64; off <<= 1) s += __shfl_xor(s, off, 64);
  const float mean = s * (1.0f/128.0f);
  const float dva = na - mean, dvb = nb - mean;
  float s2v = dva*dva + dvb*dvb;
  #pragma unroll
  for (int off = 1; off < 64; off <<= 1) s2v += __shfl_xor(s2v, off, 64);
  const float stdv = fmaxf(fsqrt(s2v * (1.0f/127.0f)), 1e-6f);
  const float rstd = frcp(stdv);

  const float2 gm = *(const float2*)(gam + lane*2);
  const float2 bt = *(const float2*)(bet + lane*2);
  const float nsa = (na - mean) * rstd * gm.x + bt.x;
  const float nsb = (nb - mean) * rstd * gm.y + bt.y;
  const float sca = fmaxf(nsa, 1e-6f) * frcp(na);
  const float scb = fmaxf(nsb, 1e-6f) * frcp(nb);
  float fa0 = oa0*sca, fa1 = oa1*sca, fa2 = oa2*sca;
  float fb0 = ob0*scb, fb1 = ob1*scb, fb2 = ob2*scb;
  const float n2a = fmaxf(fsqrt(fa0*fa0 + fa1*fa1 + fa2*fa2), 1e-6f);
  const float n2b = fmaxf(fsqrt(fb0*fb0 + fb1*fb1 + fb2*fb2), 1e-6f);
  const float c2a = fminf(50.0f * frcp(n2a), 1.0f);
  const float c2b = fminf(50.0f * frcp(n2b), 1.0f);

  float* op = out + (size_t)bn * (CC*3) + lane*6;
  floatx4u o4; o4.x = fa0*c2a; o4.y = fa1*c2a; o4.z = fa2*c2a; o4.w = fb0*c2b;
  *(floatx4u*)op = o4;
  *(float2*)(op+4) = make_float2(fb1*c2b, fb2*c2b);
}

// ---------------------------------------------------------------------------
extern "C" void kernel_launch(void* const* d_in, const int* in_sizes, int n_in,
                              void* d_out, int out_size, void* d_ws, size_t ws_size,
                              hipStream_t stream) {
  (void)in_sizes; (void)n_in; (void)out_size; (void)ws_size;
  const float* x   = (const float*)d_in[0];
  const float* v   = (const float*)d_in[1];
  const float* Wq  = (const float*)d_in[2];
  const float* Wk  = (const float*)d_in[3];
  const float* Wu  = (const float*)d_in[4];
  const float* W1  = (const float*)d_in[5];
  const float* b1  = (const float*)d_in[6];
  const float* W2  = (const float*)d_in[7];
  const float* b2  = (const float*)d_in[8];
  const float* W3  = (const float*)d_in[9];
  const float* b3  = (const float*)d_in[10];
  const float* gam = (const float*)d_in[11];
  const float* bet = (const float*)d_in[12];
  float* out = (float*)d_out;

  char* ws = (char*)d_ws;
  int*   idx = (int*)ws;                                  // BN*16 ints (1 MB)
  float* Q   = (float*)(ws + (size_t)BN * KNB * 4);       // BN*384 floats
  float* Kt  = Q  + (size_t)BN * CC * 3;
  float* U   = Kt + (size_t)BN * CC * 3;
  unsigned short* Whl = (unsigned short*)(U + (size_t)BN * CC * 3);  // 3*2*128*128 bf16
  float* warr = (float*)((char*)Whl + (size_t)3 * 2 * CC * CC * 2);  // BN*16 floats (1 MB)
  double* sqd = (double*)(warr + (size_t)BN * KNB);       // BN doubles (128 KB)
  float4* x4  = (float4*)(sqd + (size_t)BN);              // BN float4 (256 KB)

  sq_kernel<<<BN/256, 256, 0, stream>>>(x, sqd, x4);
  knn_kernel<<<BN/4, 256, 0, stream>>>(x4, sqd, idx);
  wconv_kernel<<<192, 256, 0, stream>>>(Wq, Wk, Wu, Whl);
  vn_gemm_mfma<<<(BN*3)/64, 256, 0, stream>>>(v, Whl, Q, Kt, U);
  attn_logits_kernel<<<BN/4, 256, 0, stream>>>(x, idx, Q, Kt,
                                               W1, b1, W2, b2, W3, b3, warr);
  attn_msg_kernel<<<BN/4, 256, 0, stream>>>(idx, Q, U, warr, gam, bet, out);
}